// Round 5
// baseline (1294.251 us; speedup 1.0000x reference)
//
#include <hip/hip_runtime.h>

#define D_ 256
#define T_ 2048
#define K_ 1024
#define L_ 8
#define B_ 16
#define BM_ 64
#define RS_ 260
#define THETA 0.5f
#define ECAP 128

typedef _Float16 f16x8 __attribute__((ext_vector_type(8)));
typedef float    f32x4 __attribute__((ext_vector_type(4)));

__device__ __forceinline__ unsigned long long packkey(float sc, unsigned cand) {
    const unsigned fb = __float_as_uint(sc);
    const unsigned ob = fb ^ ((unsigned)((int)fb >> 31) | 0x80000000u);
    return (((unsigned long long)ob) << 32) | cand;
}
__device__ __forceinline__ float unpackf(unsigned long long key) {
    const unsigned ob = (unsigned)(key >> 32);
    const unsigned fb = (ob & 0x80000000u) ? (ob ^ 0x80000000u) : ~ob;
    return __uint_as_float(fb);
}

// ---------------------------------------------------------------------------
// Prep 1 (validated R1/R2): ww[l*K + c] = ||codebook[l][c]||^2
// ---------------------------------------------------------------------------
__global__ __launch_bounds__(256, 4)
void rvq_ww_kernel(const float* __restrict__ cb, float* __restrict__ ww) {
    const int row  = blockIdx.x * 4 + (threadIdx.x >> 6);
    const int lane = threadIdx.x & 63;
    const float4 v = *reinterpret_cast<const float4*>(cb + (size_t)row * D_ + (lane << 2));
    float s = v.x * v.x + v.y * v.y + v.z * v.z + v.w * v.w;
    #pragma unroll
    for (int off = 1; off < 64; off <<= 1) s += __shfl_xor(s, off, 64);
    if (lane == 0) ww[row] = s;
}

// ---------------------------------------------------------------------------
// Prep 2: codebooks f32 -> f16
// ---------------------------------------------------------------------------
__global__ __launch_bounds__(256)
void rvq_cvt_kernel(const float* __restrict__ cb, _Float16* __restrict__ cb16) {
    const int i = (blockIdx.x * 256 + threadIdx.x) * 8;
    const float4 a = *reinterpret_cast<const float4*>(cb + i);
    const float4 b = *reinterpret_cast<const float4*>(cb + i + 4);
    f16x8 v;
    v[0] = (_Float16)a.x; v[1] = (_Float16)a.y; v[2] = (_Float16)a.z; v[3] = (_Float16)a.w;
    v[4] = (_Float16)b.x; v[5] = (_Float16)b.y; v[6] = (_Float16)b.z; v[7] = (_Float16)b.w;
    *reinterpret_cast<f16x8*>(cb16 + i) = v;
}

// ---------------------------------------------------------------------------
// Main: 4 waves x 16 tokens. f32 residual in LDS (R1 layout). MFMA f16 screen
// (R4 structure, full 1024 coverage) -> theta window -> exact passes with
// BITWISE-R1 arithmetic (sequential 256-fmaf chain, R1 rr tree).
// ---------------------------------------------------------------------------
__global__ __launch_bounds__(256, 2)
void rvq_main_kernel(const float* __restrict__ x, const float* __restrict__ cbf,
                     const _Float16* __restrict__ cb16, const float* __restrict__ ww,
                     float* __restrict__ out) {
    __shared__ float    rf[BM_ * RS_];
    __shared__ unsigned elist[4][ECAP];
    __shared__ int      ecnt[4];

    const int tid  = threadIdx.x;
    const int lane = tid & 63;
    const int wv   = tid >> 6;
    const int c4   = lane & 15;          // token within wave tile (0..15)
    const int g    = lane >> 4;          // d-group (0..3)
    const int tok0 = blockIdx.x * BM_;
    const int b    = tok0 >> 11;
    const int tb   = tok0 & (T_ - 1);
    const int trow = wv * 16 + c4;       // my token's LDS row

    // stage x -> rf (VERBATIM R1 pattern)
    for (int i = tid; i < BM_ * D_; i += 256) {
        const int d = i >> 6, t = i & 63;
        rf[t * RS_ + d] = x[((size_t)b * D_ + d) * T_ + tb + t];
    }
    __syncthreads();

    #pragma unroll 1
    for (int l = 0; l < L_; ++l) {
        __syncthreads();                 // wave lockstep for L1 dedup
        if (lane == 0) ecnt[wv] = 0;

        const _Float16* __restrict__ cbl6 = cb16 + (size_t)l * K_ * D_;
        const float*    __restrict__ cblf = cbf  + (size_t)l * K_ * D_;
        const float*    __restrict__ wwl  = ww + l * K_;

        // rr per token — VERBATIM R1 tree (float4 self-dot + 64-lane butterfly)
        float rrv = 0.0f;
        #pragma unroll 1
        for (int tt = 0; tt < 16; ++tt) {
            const float4 v = *reinterpret_cast<const float4*>(
                rf + (wv * 16 + tt) * RS_ + (lane << 2));
            float s = v.x * v.x + v.y * v.y + v.z * v.z + v.w * v.w;
            #pragma unroll
            for (int off = 1; off < 64; off <<= 1) s += __shfl_xor(s, off, 64);
            if (c4 == tt) rrv = s;
        }

        // f16 A-fragments from LDS f32 residual
        f16x8 fr[8];
        {
            const float* rp0 = rf + trow * RS_;
            #pragma unroll
            for (int kk = 0; kk < 8; ++kk) {
                const float4 a = *reinterpret_cast<const float4*>(rp0 + kk * 32 + g * 8);
                const float4 b2 = *reinterpret_cast<const float4*>(rp0 + kk * 32 + g * 8 + 4);
                fr[kk][0] = (_Float16)a.x;  fr[kk][1] = (_Float16)a.y;
                fr[kk][2] = (_Float16)a.z;  fr[kk][3] = (_Float16)a.w;
                fr[kk][4] = (_Float16)b2.x; fr[kk][5] = (_Float16)b2.y;
                fr[kk][6] = (_Float16)b2.z; fr[kk][7] = (_Float16)b2.w;
            }
        }

        // ---- screen: 8 chunks x 128 cands = ALL 1024 (R4 structure) ----
        unsigned long long bkey[4];
        #pragma unroll
        for (int j = 0; j < 4; ++j) bkey[j] = packkey(__builtin_inff(), 0u);

        #pragma unroll 1
        for (int ch = 0; ch < 8; ++ch) {
            const int base = ch * 128;
            f32x4 acc[8];
            #pragma unroll
            for (int n = 0; n < 8; ++n) acc[n] = (f32x4){0.f, 0.f, 0.f, 0.f};

            #pragma unroll
            for (int kk = 0; kk < 8; ++kk) {
                #pragma unroll
                for (int n = 0; n < 8; ++n) {
                    const f16x8 bf = *reinterpret_cast<const f16x8*>(
                        cbl6 + (size_t)(base + n * 16 + c4) * D_ + kk * 32 + g * 8);
                    acc[n] = __builtin_amdgcn_mfma_f32_16x16x32_f16(fr[kk], bf, acc[n], 0, 0, 0);
                }
            }

            float wwv[8];
            #pragma unroll
            for (int n = 0; n < 8; ++n) wwv[n] = wwl[base + n * 16 + c4];
            #pragma unroll
            for (int n = 0; n < 8; ++n)
                #pragma unroll
                for (int j = 0; j < 4; ++j)
                    acc[n][j] = fmaf(-2.0f, acc[n][j], wwv[n]);   // screen score

            unsigned long long ckey[4];
            float cm[4];
            #pragma unroll
            for (int j = 0; j < 4; ++j) {
                float ms = acc[0][j];
                unsigned mc = (unsigned)(base + c4);
                #pragma unroll
                for (int n = 1; n < 8; ++n) {
                    const bool lt = acc[n][j] < ms;
                    ms = lt ? acc[n][j] : ms;
                    mc = lt ? (unsigned)(base + n * 16 + c4) : mc;
                }
                unsigned long long k0 = packkey(ms, mc);
                #pragma unroll
                for (int off = 1; off < 16; off <<= 1) {
                    const unsigned long long k2 = __shfl_xor(k0, off, 64);
                    if (k2 < k0) k0 = k2;
                }
                ckey[j] = k0;
                cm[j] = unpackf(k0);

                if (k0 < bkey[j]) {
                    if (c4 == 0 && unpackf(bkey[j]) <= cm[j] + THETA) {
                        const int p = atomicAdd(&ecnt[wv], 1);
                        if (p < ECAP)
                            elist[wv][p] = (((unsigned)(bkey[j] & 0xffffffffull)) << 4) |
                                           (unsigned)(g * 4 + j);
                    }
                    bkey[j] = k0;
                } else {
                    if (c4 == 0 && cm[j] <= unpackf(bkey[j]) + THETA) {
                        const int p = atomicAdd(&ecnt[wv], 1);
                        if (p < ECAP)
                            elist[wv][p] = (((unsigned)(k0 & 0xffffffffull)) << 4) |
                                           (unsigned)(g * 4 + j);
                    }
                }
            }

            #pragma unroll
            for (int n = 0; n < 8; ++n)
                #pragma unroll
                for (int j = 0; j < 4; ++j) {
                    const unsigned cand = (unsigned)(base + n * 16 + c4);
                    if (acc[n][j] <= cm[j] + THETA &&
                        packkey(acc[n][j], cand) != ckey[j]) {
                        const int p = atomicAdd(&ecnt[wv], 1);
                        if (p < ECAP)
                            elist[wv][p] = (cand << 4) | (unsigned)(g * 4 + j);
                    }
                }
        }

        // broadcast approx winner to owner lanes (token c4)
        unsigned bc0 = (unsigned)(bkey[0] & 0xffffffffull);
        unsigned bc1 = (unsigned)(bkey[1] & 0xffffffffull);
        unsigned bc2 = (unsigned)(bkey[2] & 0xffffffffull);
        unsigned bc3 = (unsigned)(bkey[3] & 0xffffffffull);
        const int srcl = (c4 >> 2) << 4;
        const unsigned w0 = __shfl(bc0, srcl, 64);
        const unsigned w1 = __shfl(bc1, srcl, 64);
        const unsigned w2 = __shfl(bc2, srcl, 64);
        const unsigned w3 = __shfl(bc3, srcl, 64);
        const unsigned wa = (c4 & 1) ? w1 : w0;
        const unsigned wb = (c4 & 1) ? w3 : w2;
        const unsigned wincand = (c4 & 2) ? wb : wa;

        // ---- exact winner pass: BITWISE-R1 sequential chain, 4 g-copies ----
        unsigned long long bestk;
        {
            const float* rp = rf + trow * RS_;
            const float* wp = cblf + (size_t)wincand * D_;
            float a0 = 0.0f;
            #pragma unroll 4
            for (int dc = 0; dc < D_; dc += 8) {
                const float4 ra = *reinterpret_cast<const float4*>(rp + dc);
                const float4 rb = *reinterpret_cast<const float4*>(rp + dc + 4);
                const float4 wa4 = *reinterpret_cast<const float4*>(wp + dc);
                const float4 wb4 = *reinterpret_cast<const float4*>(wp + dc + 4);
                a0 = fmaf(wa4.x, ra.x, a0);
                a0 = fmaf(wa4.y, ra.y, a0);
                a0 = fmaf(wa4.z, ra.z, a0);
                a0 = fmaf(wa4.w, ra.w, a0);
                a0 = fmaf(wb4.x, rb.x, a0);
                a0 = fmaf(wb4.y, rb.y, a0);
                a0 = fmaf(wb4.z, rb.z, a0);
                a0 = fmaf(wb4.w, rb.w, a0);
            }
            const float scw = __fadd_rn(__fsub_rn(rrv, __fmul_rn(2.0f, a0)), wwl[wincand]);
            bestk = packkey(scw, wincand);
        }

        // ---- extras: serial, same bitwise-R1 chain on 4 redundant lanes ----
        int ne = ecnt[wv];
        ne = min(ne, ECAP);
        #pragma unroll 1
        for (int i = 0; i < ne; ++i) {
            const unsigned e  = elist[wv][i];
            const unsigned ec = e >> 4;
            const int      et = (int)(e & 15u);
            if (c4 == et) {
                const float* rp = rf + trow * RS_;
                const float* ep = cblf + (size_t)ec * D_;
                float q = 0.0f;
                #pragma unroll 4
                for (int dc = 0; dc < D_; dc += 8) {
                    const float4 ra = *reinterpret_cast<const float4*>(rp + dc);
                    const float4 rb = *reinterpret_cast<const float4*>(rp + dc + 4);
                    const float4 wa4 = *reinterpret_cast<const float4*>(ep + dc);
                    const float4 wb4 = *reinterpret_cast<const float4*>(ep + dc + 4);
                    q = fmaf(wa4.x, ra.x, q);
                    q = fmaf(wa4.y, ra.y, q);
                    q = fmaf(wa4.z, ra.z, q);
                    q = fmaf(wa4.w, ra.w, q);
                    q = fmaf(wb4.x, rb.x, q);
                    q = fmaf(wb4.y, rb.y, q);
                    q = fmaf(wb4.z, rb.z, q);
                    q = fmaf(wb4.w, rb.w, q);
                }
                const float sce = __fadd_rn(__fsub_rn(rrv, __fmul_rn(2.0f, q)), wwl[ec]);
                const unsigned long long k2 = packkey(sce, ec);
                if (k2 < bestk) bestk = k2;
            }
        }

        const unsigned fc = (unsigned)(bestk & 0xffffffffull);
        if (g == 0)
            out[(size_t)B_ * D_ * T_ + ((size_t)b * L_ + l) * T_ + tb + wv * 16 + c4] =
                (float)fc;

        // ---- residual update (VERBATIM R1 semantics), per-token ----
        #pragma unroll 1
        for (int tt = 0; tt < 16; ++tt) {
            const int fcb = __shfl((int)fc, tt, 64);   // lane tt = (g=0, c4=tt)
            const float4 wq = *reinterpret_cast<const float4*>(
                cblf + (size_t)fcb * D_ + (lane << 2));
            float* rp2 = rf + (wv * 16 + tt) * RS_ + (lane << 2);
            float4 rv = *reinterpret_cast<float4*>(rp2);
            rv.x = __fsub_rn(rv.x, wq.x);
            rv.y = __fsub_rn(rv.y, wq.y);
            rv.z = __fsub_rn(rv.z, wq.z);
            rv.w = __fsub_rn(rv.w, wq.w);
            *reinterpret_cast<float4*>(rp2) = rv;
        }
    }

    __syncthreads();
    // epilogue (VERBATIM R1): quantized = x - r_final
    for (int i = tid; i < BM_ * D_; i += 256) {
        const int d = i >> 6, t = i & 63;
        const size_t gi = ((size_t)b * D_ + d) * T_ + tb + t;
        out[gi] = __fsub_rn(x[gi], rf[t * RS_ + d]);
    }
}

extern "C" void kernel_launch(void* const* d_in, const int* in_sizes, int n_in,
                              void* d_out, int out_size, void* d_ws, size_t ws_size,
                              hipStream_t stream) {
    const float* x  = (const float*)d_in[0];
    const float* cb = (const float*)d_in[1];
    float* out = (float*)d_out;
    float*    ww   = (float*)d_ws;                       // 32 KB
    _Float16* cb16 = (_Float16*)((char*)d_ws + 32768);   // 4 MB

    hipLaunchKernelGGL(rvq_ww_kernel,  dim3((L_ * K_) / 4), dim3(256), 0, stream, cb, ww);
    hipLaunchKernelGGL(rvq_cvt_kernel, dim3((L_ * K_ * D_) / 2048), dim3(256), 0, stream, cb, cb16);
    hipLaunchKernelGGL(rvq_main_kernel, dim3((B_ * T_) / BM_), dim3(256), 0, stream,
                       x, cb, cb16, ww, out);
}

// Round 6
// 1187.493 us; speedup vs baseline: 1.0899x; 1.0899x over previous
//
#include <hip/hip_runtime.h>

#define D_ 256
#define T_ 2048
#define K_ 1024
#define L_ 8
#define B_ 16
#define BM_ 64
#define RS_ 260
#define THETA 0.5f
#define ECT 24

typedef _Float16 f16x8 __attribute__((ext_vector_type(8)));
typedef float    f32x4 __attribute__((ext_vector_type(4)));

__device__ __forceinline__ unsigned long long packkey(float sc, unsigned cand) {
    const unsigned fb = __float_as_uint(sc);
    const unsigned ob = fb ^ ((unsigned)((int)fb >> 31) | 0x80000000u);
    return (((unsigned long long)ob) << 32) | cand;
}
__device__ __forceinline__ float unpackf(unsigned long long key) {
    const unsigned ob = (unsigned)(key >> 32);
    const unsigned fb = (ob & 0x80000000u) ? (ob ^ 0x80000000u) : ~ob;
    return __uint_as_float(fb);
}

// ---------------------------------------------------------------------------
// Prep 1 (validated): ww[l*K + c] = ||codebook[l][c]||^2
// ---------------------------------------------------------------------------
__global__ __launch_bounds__(256, 4)
void rvq_ww_kernel(const float* __restrict__ cb, float* __restrict__ ww) {
    const int row  = blockIdx.x * 4 + (threadIdx.x >> 6);
    const int lane = threadIdx.x & 63;
    const float4 v = *reinterpret_cast<const float4*>(cb + (size_t)row * D_ + (lane << 2));
    float s = v.x * v.x + v.y * v.y + v.z * v.z + v.w * v.w;
    #pragma unroll
    for (int off = 1; off < 64; off <<= 1) s += __shfl_xor(s, off, 64);
    if (lane == 0) ww[row] = s;
}

// ---------------------------------------------------------------------------
// Prep 2: codebooks f32 -> f16
// ---------------------------------------------------------------------------
__global__ __launch_bounds__(256)
void rvq_cvt_kernel(const float* __restrict__ cb, _Float16* __restrict__ cb16) {
    const int i = (blockIdx.x * 256 + threadIdx.x) * 8;
    const float4 a = *reinterpret_cast<const float4*>(cb + i);
    const float4 b = *reinterpret_cast<const float4*>(cb + i + 4);
    f16x8 v;
    v[0] = (_Float16)a.x; v[1] = (_Float16)a.y; v[2] = (_Float16)a.z; v[3] = (_Float16)a.w;
    v[4] = (_Float16)b.x; v[5] = (_Float16)b.y; v[6] = (_Float16)b.z; v[7] = (_Float16)b.w;
    *reinterpret_cast<f16x8*>(cb16 + i) = v;
}

// ---------------------------------------------------------------------------
// Main (R6): R5 exactness frozen; screen with depth-4 register-ring B
// prefetch; per-token extras lists drained in parallel by c4-groups;
// prefetched residual-update gathers.
// ---------------------------------------------------------------------------
__global__ __launch_bounds__(256, 2)
void rvq_main_kernel(const float* __restrict__ x, const float* __restrict__ cbf,
                     const _Float16* __restrict__ cb16, const float* __restrict__ ww,
                     float* __restrict__ out) {
    __shared__ float    rf[BM_ * RS_];
    __shared__ unsigned elist[4][16][ECT];
    __shared__ int      ecnt[4][16];

    const int tid  = threadIdx.x;
    const int lane = tid & 63;
    const int wv   = tid >> 6;
    const int c4   = lane & 15;          // token within wave tile (0..15)
    const int g    = lane >> 4;          // d-group (0..3)
    const int tok0 = blockIdx.x * BM_;
    const int b    = tok0 >> 11;
    const int tb   = tok0 & (T_ - 1);
    const int trow = wv * 16 + c4;       // my token's LDS row

    // stage x -> rf (VERBATIM R1/R5 pattern)
    for (int i = tid; i < BM_ * D_; i += 256) {
        const int d = i >> 6, t = i & 63;
        rf[t * RS_ + d] = x[((size_t)b * D_ + d) * T_ + tb + t];
    }
    __syncthreads();

    #pragma unroll 1
    for (int l = 0; l < L_; ++l) {
        __syncthreads();                 // wave lockstep for L1 dedup
        if (lane < 16) ecnt[wv][lane] = 0;

        const _Float16* __restrict__ cbl6 = cb16 + (size_t)l * K_ * D_;
        const float*    __restrict__ cblf = cbf  + (size_t)l * K_ * D_;
        const float*    __restrict__ wwl  = ww + l * K_;

        // rr per token — VERBATIM R1 tree (float4 self-dot + 64-lane butterfly)
        float rrv = 0.0f;
        #pragma unroll 1
        for (int tt = 0; tt < 16; ++tt) {
            const float4 v = *reinterpret_cast<const float4*>(
                rf + (wv * 16 + tt) * RS_ + (lane << 2));
            float s = v.x * v.x + v.y * v.y + v.z * v.z + v.w * v.w;
            #pragma unroll
            for (int off = 1; off < 64; off <<= 1) s += __shfl_xor(s, off, 64);
            if (c4 == tt) rrv = s;
        }

        // f16 A-fragments from LDS f32 residual
        f16x8 fr[8];
        {
            const float* rp0 = rf + trow * RS_;
            #pragma unroll
            for (int kk = 0; kk < 8; ++kk) {
                const float4 a  = *reinterpret_cast<const float4*>(rp0 + kk * 32 + g * 8);
                const float4 b2 = *reinterpret_cast<const float4*>(rp0 + kk * 32 + g * 8 + 4);
                fr[kk][0] = (_Float16)a.x;  fr[kk][1] = (_Float16)a.y;
                fr[kk][2] = (_Float16)a.z;  fr[kk][3] = (_Float16)a.w;
                fr[kk][4] = (_Float16)b2.x; fr[kk][5] = (_Float16)b2.y;
                fr[kk][6] = (_Float16)b2.z; fr[kk][7] = (_Float16)b2.w;
            }
        }

        // ---- screen: 8 chunks x 128 cands, depth-4 register-ring B ----
        unsigned long long bkey[4];
        #pragma unroll
        for (int j = 0; j < 4; ++j) bkey[j] = packkey(__builtin_inff(), 0u);

        f16x8 bf[4][8];
        #pragma unroll
        for (int pk = 0; pk < 4; ++pk)
            #pragma unroll
            for (int n = 0; n < 8; ++n)
                bf[pk][n] = *reinterpret_cast<const f16x8*>(
                    cbl6 + (size_t)(n * 16 + c4) * D_ + pk * 32 + g * 8);

        #pragma unroll 1
        for (int ch = 0; ch < 8; ++ch) {
            const int base = ch * 128;
            f32x4 acc[8];
            #pragma unroll
            for (int n = 0; n < 8; ++n) acc[n] = (f32x4){0.f, 0.f, 0.f, 0.f};

            #pragma unroll
            for (int kk = 0; kk < 8; ++kk) {
                #pragma unroll
                for (int n = 0; n < 8; ++n)
                    acc[n] = __builtin_amdgcn_mfma_f32_16x16x32_f16(
                        fr[kk], bf[kk & 3][n], acc[n], 0, 0, 0);
                // refill slot kk&3 with step s+4 (ch,kk+4) or (ch+1,kk-4)
                const int nch = (kk < 4) ? ch : ch + 1;
                const int nkk = (kk < 4) ? kk + 4 : kk - 4;
                if (nch < 8) {
                    const int nb = nch * 128;
                    #pragma unroll
                    for (int n = 0; n < 8; ++n)
                        bf[kk & 3][n] = *reinterpret_cast<const f16x8*>(
                            cbl6 + (size_t)(nb + n * 16 + c4) * D_ + nkk * 32 + g * 8);
                }
            }

            float wwv[8];
            #pragma unroll
            for (int n = 0; n < 8; ++n) wwv[n] = wwl[base + n * 16 + c4];
            #pragma unroll
            for (int n = 0; n < 8; ++n)
                #pragma unroll
                for (int j = 0; j < 4; ++j)
                    acc[n][j] = fmaf(-2.0f, acc[n][j], wwv[n]);   // screen score

            unsigned long long ckey[4];
            float cm[4];
            #pragma unroll
            for (int j = 0; j < 4; ++j) {
                const int tj = g * 4 + j;            // token of this acc row
                float ms = acc[0][j];
                unsigned mc = (unsigned)(base + c4);
                #pragma unroll
                for (int n = 1; n < 8; ++n) {
                    const bool lt = acc[n][j] < ms;
                    ms = lt ? acc[n][j] : ms;
                    mc = lt ? (unsigned)(base + n * 16 + c4) : mc;
                }
                unsigned long long k0 = packkey(ms, mc);
                #pragma unroll
                for (int off = 1; off < 16; off <<= 1) {
                    const unsigned long long k2 = __shfl_xor(k0, off, 64);
                    if (k2 < k0) k0 = k2;
                }
                ckey[j] = k0;
                cm[j] = unpackf(k0);

                if (k0 < bkey[j]) {
                    if (c4 == 0 && unpackf(bkey[j]) <= cm[j] + THETA) {
                        const int p = atomicAdd(&ecnt[wv][tj], 1);
                        if (p < ECT)
                            elist[wv][tj][p] = (unsigned)(bkey[j] & 0xffffffffull);
                    }
                    bkey[j] = k0;
                } else {
                    if (c4 == 0 && cm[j] <= unpackf(bkey[j]) + THETA) {
                        const int p = atomicAdd(&ecnt[wv][tj], 1);
                        if (p < ECT)
                            elist[wv][tj][p] = (unsigned)(k0 & 0xffffffffull);
                    }
                }
            }

            #pragma unroll
            for (int n = 0; n < 8; ++n)
                #pragma unroll
                for (int j = 0; j < 4; ++j) {
                    const unsigned cand = (unsigned)(base + n * 16 + c4);
                    if (acc[n][j] <= cm[j] + THETA &&
                        packkey(acc[n][j], cand) != ckey[j]) {
                        const int tj = g * 4 + j;
                        const int p = atomicAdd(&ecnt[wv][tj], 1);
                        if (p < ECT) elist[wv][tj][p] = cand;
                    }
                }
        }

        // broadcast approx winner to owner lanes (token c4)
        unsigned bc0 = (unsigned)(bkey[0] & 0xffffffffull);
        unsigned bc1 = (unsigned)(bkey[1] & 0xffffffffull);
        unsigned bc2 = (unsigned)(bkey[2] & 0xffffffffull);
        unsigned bc3 = (unsigned)(bkey[3] & 0xffffffffull);
        const int srcl = (c4 >> 2) << 4;
        const unsigned w0 = __shfl(bc0, srcl, 64);
        const unsigned w1 = __shfl(bc1, srcl, 64);
        const unsigned w2 = __shfl(bc2, srcl, 64);
        const unsigned w3 = __shfl(bc3, srcl, 64);
        const unsigned wa = (c4 & 1) ? w1 : w0;
        const unsigned wb = (c4 & 1) ? w3 : w2;
        const unsigned wincand = (c4 & 2) ? wb : wa;

        // ---- exact winner pass: BITWISE-R1 sequential chain (frozen) ----
        unsigned long long bestk;
        {
            const float* rp = rf + trow * RS_;
            const float* wp = cblf + (size_t)wincand * D_;
            float a0 = 0.0f;
            #pragma unroll 4
            for (int dc = 0; dc < D_; dc += 8) {
                const float4 ra = *reinterpret_cast<const float4*>(rp + dc);
                const float4 rb = *reinterpret_cast<const float4*>(rp + dc + 4);
                const float4 wa4 = *reinterpret_cast<const float4*>(wp + dc);
                const float4 wb4 = *reinterpret_cast<const float4*>(wp + dc + 4);
                a0 = fmaf(wa4.x, ra.x, a0);
                a0 = fmaf(wa4.y, ra.y, a0);
                a0 = fmaf(wa4.z, ra.z, a0);
                a0 = fmaf(wa4.w, ra.w, a0);
                a0 = fmaf(wb4.x, rb.x, a0);
                a0 = fmaf(wb4.y, rb.y, a0);
                a0 = fmaf(wb4.z, rb.z, a0);
                a0 = fmaf(wb4.w, rb.w, a0);
            }
            const float scw = __fadd_rn(__fsub_rn(rrv, __fmul_rn(2.0f, a0)), wwl[wincand]);
            bestk = packkey(scw, wincand);
        }

        // ---- extras: per-token lists, c4-groups drain in parallel ----
        {
            const int nt = min(ecnt[wv][c4], ECT);
            const float* rp = rf + trow * RS_;
            #pragma unroll 1
            for (int i = 0; i < nt; ++i) {
                const unsigned ec = elist[wv][c4][i];
                const float* ep = cblf + (size_t)ec * D_;
                float q = 0.0f;
                #pragma unroll 4
                for (int dc = 0; dc < D_; dc += 8) {
                    const float4 ra = *reinterpret_cast<const float4*>(rp + dc);
                    const float4 rb = *reinterpret_cast<const float4*>(rp + dc + 4);
                    const float4 wa4 = *reinterpret_cast<const float4*>(ep + dc);
                    const float4 wb4 = *reinterpret_cast<const float4*>(ep + dc + 4);
                    q = fmaf(wa4.x, ra.x, q);
                    q = fmaf(wa4.y, ra.y, q);
                    q = fmaf(wa4.z, ra.z, q);
                    q = fmaf(wa4.w, ra.w, q);
                    q = fmaf(wb4.x, rb.x, q);
                    q = fmaf(wb4.y, rb.y, q);
                    q = fmaf(wb4.z, rb.z, q);
                    q = fmaf(wb4.w, rb.w, q);
                }
                const float sce = __fadd_rn(__fsub_rn(rrv, __fmul_rn(2.0f, q)), wwl[ec]);
                const unsigned long long k2 = packkey(sce, ec);
                if (k2 < bestk) bestk = k2;
            }
        }

        const unsigned fc = (unsigned)(bestk & 0xffffffffull);
        if (g == 0)
            out[(size_t)B_ * D_ * T_ + ((size_t)b * L_ + l) * T_ + tb + wv * 16 + c4] =
                (float)fc;

        // ---- residual update (frozen semantics), prefetched gathers ----
        {
            float4 wq[16];
            #pragma unroll
            for (int tt = 0; tt < 16; ++tt) {
                const int fcb = __shfl((int)fc, tt, 64);   // lane tt = (g=0,c4=tt)
                wq[tt] = *reinterpret_cast<const float4*>(
                    cblf + (size_t)fcb * D_ + (lane << 2));
            }
            #pragma unroll
            for (int tt = 0; tt < 16; ++tt) {
                float* rp2 = rf + (wv * 16 + tt) * RS_ + (lane << 2);
                float4 rv = *reinterpret_cast<float4*>(rp2);
                rv.x = __fsub_rn(rv.x, wq[tt].x);
                rv.y = __fsub_rn(rv.y, wq[tt].y);
                rv.z = __fsub_rn(rv.z, wq[tt].z);
                rv.w = __fsub_rn(rv.w, wq[tt].w);
                *reinterpret_cast<float4*>(rp2) = rv;
            }
        }
    }

    __syncthreads();
    // epilogue (frozen): quantized = x - r_final
    for (int i = tid; i < BM_ * D_; i += 256) {
        const int d = i >> 6, t = i & 63;
        const size_t gi = ((size_t)b * D_ + d) * T_ + tb + t;
        out[gi] = __fsub_rn(x[gi], rf[t * RS_ + d]);
    }
}

extern "C" void kernel_launch(void* const* d_in, const int* in_sizes, int n_in,
                              void* d_out, int out_size, void* d_ws, size_t ws_size,
                              hipStream_t stream) {
    const float* x  = (const float*)d_in[0];
    const float* cb = (const float*)d_in[1];
    float* out = (float*)d_out;
    float*    ww   = (float*)d_ws;                       // 32 KB
    _Float16* cb16 = (_Float16*)((char*)d_ws + 32768);   // 4 MB

    hipLaunchKernelGGL(rvq_ww_kernel,  dim3((L_ * K_) / 4), dim3(256), 0, stream, cb, ww);
    hipLaunchKernelGGL(rvq_cvt_kernel, dim3((L_ * K_ * D_) / 2048), dim3(256), 0, stream, cb, cb16);
    hipLaunchKernelGGL(rvq_main_kernel, dim3((B_ * T_) / BM_), dim3(256), 0, stream,
                       x, cb, cb16, ww, out);
}

// Round 7
// 1102.755 us; speedup vs baseline: 1.1737x; 1.0768x over previous
//
#include <hip/hip_runtime.h>

#define D_ 256
#define T_ 2048
#define K_ 1024
#define L_ 8
#define B_ 16
#define THETA 0.5f
#define ECT 24

typedef _Float16 f16x8 __attribute__((ext_vector_type(8)));
typedef float    f32x4 __attribute__((ext_vector_type(4)));

__device__ __forceinline__ unsigned long long packkey(float sc, unsigned cand) {
    const unsigned fb = __float_as_uint(sc);
    const unsigned ob = fb ^ ((unsigned)((int)fb >> 31) | 0x80000000u);
    return (((unsigned long long)ob) << 32) | cand;
}
__device__ __forceinline__ float unpackf(unsigned long long key) {
    const unsigned ob = (unsigned)(key >> 32);
    const unsigned fb = (ob & 0x80000000u) ? (ob ^ 0x80000000u) : ~ob;
    return __uint_as_float(fb);
}

// ---------------------------------------------------------------------------
// Prep 1 (validated): ww[l*K + c] = ||codebook[l][c]||^2
// ---------------------------------------------------------------------------
__global__ __launch_bounds__(256, 4)
void rvq_ww_kernel(const float* __restrict__ cb, float* __restrict__ ww) {
    const int row  = blockIdx.x * 4 + (threadIdx.x >> 6);
    const int lane = threadIdx.x & 63;
    const float4 v = *reinterpret_cast<const float4*>(cb + (size_t)row * D_ + (lane << 2));
    float s = v.x * v.x + v.y * v.y + v.z * v.z + v.w * v.w;
    #pragma unroll
    for (int off = 1; off < 64; off <<= 1) s += __shfl_xor(s, off, 64);
    if (lane == 0) ww[row] = s;
}

// ---------------------------------------------------------------------------
// Prep 2: codebooks f32 -> f16 (linear layout)
// ---------------------------------------------------------------------------
__global__ __launch_bounds__(256)
void rvq_cvt_kernel(const float* __restrict__ cb, _Float16* __restrict__ cb16) {
    const int i = (blockIdx.x * 256 + threadIdx.x) * 8;
    const float4 a = *reinterpret_cast<const float4*>(cb + i);
    const float4 b = *reinterpret_cast<const float4*>(cb + i + 4);
    f16x8 v;
    v[0] = (_Float16)a.x; v[1] = (_Float16)a.y; v[2] = (_Float16)a.z; v[3] = (_Float16)a.w;
    v[4] = (_Float16)b.x; v[5] = (_Float16)b.y; v[6] = (_Float16)b.z; v[7] = (_Float16)b.w;
    *reinterpret_cast<f16x8*>(cb16 + i) = v;
}

// ---------------------------------------------------------------------------
// Main (R7): register-resident residual; block-shared double-buffered LDS B
// (reg-staged, XOR-swizzled); f16 MFMA screen (scores bitwise == R6);
// theta window; exact passes via 4-lane relay executing R1's sequential
// 256-fmaf chain in exact order; rr via bitwise-equivalent tree.
// ---------------------------------------------------------------------------
__global__ __launch_bounds__(256, 1)
void rvq_main_kernel(const float* __restrict__ x, const float* __restrict__ cbf,
                     const _Float16* __restrict__ cb16, const float* __restrict__ ww,
                     float* __restrict__ out) {
    __shared__ __align__(16) _Float16 bstage[2][32768];   // 2 x 64 KB B tiles
    __shared__ unsigned elist[4][16][ECT];
    __shared__ int      ecnt[4][16];

    const int tid  = threadIdx.x;
    const int lane = tid & 63;
    const int wv   = tid >> 6;
    const int c4   = lane & 15;          // token within wave tile
    const int g    = lane >> 4;          // d-group
    const int tg   = blockIdx.x * 64 + wv * 16 + c4;
    const int b    = tg >> 11;
    const int tl   = tg & (T_ - 1);
    const size_t xbase = ((size_t)b << 19) + tl;

    // residual f32 in regs: r_[kk*8+e] = r[token c4][d = kk*32 + g*8 + e]
    float r_[64];
    #pragma unroll
    for (int kk = 0; kk < 8; ++kk)
        #pragma unroll
        for (int e = 0; e < 8; ++e)
            r_[kk * 8 + e] = x[xbase + (size_t)(kk * 32 + g * 8 + e) * T_];

    // swizzled LDS read offset (entry units): lp2 = (4*c4+g) ^ (c4>>1)
    const int lp2 = ((c4 << 2) | g) ^ ((c4 >> 1) & 7);

    #pragma unroll 1
    for (int l = 0; l < L_; ++l) {
        const _Float16* __restrict__ cbl6 = cb16 + (size_t)l * K_ * D_;
        const float*    __restrict__ cblf = cbf  + (size_t)l * K_ * D_;
        const float*    __restrict__ wwl  = ww + l * K_;

        if (lane < 16) ecnt[wv][lane] = 0;

        // ---- rr: bitwise-equivalent reconstruction of R1's butterfly ----
        // leaves s_i over d=4i..4i+3 with R1's exact expression; tree by
        // commutative pairwise combines (proven order-equivalent).
        float rrv;
        {
            float Tk[8];
            #pragma unroll
            for (int kk = 0; kk < 8; ++kk) {
                float4 v;
                v.x = r_[kk * 8 + 0]; v.y = r_[kk * 8 + 1];
                v.z = r_[kk * 8 + 2]; v.w = r_[kk * 8 + 3];
                float s = v.x * v.x + v.y * v.y + v.z * v.z + v.w * v.w;
                float4 u;
                u.x = r_[kk * 8 + 4]; u.y = r_[kk * 8 + 5];
                u.z = r_[kk * 8 + 6]; u.w = r_[kk * 8 + 7];
                float s2 = u.x * u.x + u.y * u.y + u.z * u.z + u.w * u.w;
                const float p  = s + s2;                 // level 1 (xor 1)
                const float po = __shfl_xor(p, 16, 64);  // g xor 1
                const float q  = p + po;                 // level 2
                const float qo = __shfl_xor(q, 32, 64);  // g xor 2
                Tk[kk] = q + qo;                         // level 3
            }
            const float u01 = Tk[0] + Tk[1], u23 = Tk[2] + Tk[3];
            const float u45 = Tk[4] + Tk[5], u67 = Tk[6] + Tk[7];
            rrv = (u01 + u23) + (u45 + u67);
        }

        // f16 A-fragments from register residual (same values as before)
        f16x8 fr[8];
        #pragma unroll
        for (int kk = 0; kk < 8; ++kk)
            #pragma unroll
            for (int e = 0; e < 8; ++e)
                fr[kk][e] = (_Float16)r_[kk * 8 + e];

        // ---- prologue: stage chunk 0 into buf0 ----
        int4 gst[16];
        #pragma unroll
        for (int i = 0; i < 16; ++i) {
            const int e = tid + (i << 8);
            const int eg = e & 3, ec = (e >> 2) & 15, en = (e >> 6) & 7, ek = (e >> 9) & 7;
            gst[i] = *reinterpret_cast<const int4*>(
                cbl6 + (size_t)(en * 16 + ec) * D_ + ek * 32 + eg * 8);
            asm volatile("" : "+v"(gst[i].x), "+v"(gst[i].y), "+v"(gst[i].z), "+v"(gst[i].w));
        }
        #pragma unroll
        for (int i = 0; i < 16; ++i) {
            const int e = tid + (i << 8);
            const int ep = e ^ ((e >> 3) & 7);
            *reinterpret_cast<int4*>(&bstage[0][ep * 8]) = gst[i];
        }
        __syncthreads();

        unsigned long long bkey[4];
        #pragma unroll
        for (int j = 0; j < 4; ++j) bkey[j] = packkey(__builtin_inff(), 0u);

        // ---- screen: 8 chunks x 128 cands; B from LDS double buffer ----
        #pragma unroll 1
        for (int ch = 0; ch < 8; ++ch) {
            // issue next chunk's global loads early (hide under compute)
            if (ch < 7) {
                const int nb = (ch + 1) * 128;
                #pragma unroll
                for (int i = 0; i < 16; ++i) {
                    const int e = tid + (i << 8);
                    const int eg = e & 3, ec = (e >> 2) & 15, en = (e >> 6) & 7, ek = (e >> 9) & 7;
                    gst[i] = *reinterpret_cast<const int4*>(
                        cbl6 + (size_t)(nb + en * 16 + ec) * D_ + ek * 32 + eg * 8);
                    asm volatile("" : "+v"(gst[i].x), "+v"(gst[i].y), "+v"(gst[i].z), "+v"(gst[i].w));
                }
            }

            const int base = ch * 128;
            const _Float16* bufp = bstage[ch & 1];
            f32x4 acc[8];
            #pragma unroll
            for (int n = 0; n < 8; ++n) acc[n] = (f32x4){0.f, 0.f, 0.f, 0.f};

            #pragma unroll
            for (int kk = 0; kk < 8; ++kk) {
                f16x8 bfv[8];
                #pragma unroll
                for (int n = 0; n < 8; ++n)
                    bfv[n] = *reinterpret_cast<const f16x8*>(
                        bufp + (size_t)(((kk * 8 + n) * 64 + lp2) * 8));
                #pragma unroll
                for (int n = 0; n < 8; ++n)
                    acc[n] = __builtin_amdgcn_mfma_f32_16x16x32_f16(fr[kk], bfv[n], acc[n], 0, 0, 0);
            }

            float wwv[8];
            #pragma unroll
            for (int n = 0; n < 8; ++n) wwv[n] = wwl[base + n * 16 + c4];
            #pragma unroll
            for (int n = 0; n < 8; ++n)
                #pragma unroll
                for (int j = 0; j < 4; ++j)
                    acc[n][j] = fmaf(-2.0f, acc[n][j], wwv[n]);   // screen score

            unsigned long long ckey[4];
            float cm[4];
            #pragma unroll
            for (int j = 0; j < 4; ++j) {
                const int tj = g * 4 + j;            // token of this acc row
                float ms = acc[0][j];
                unsigned mc = (unsigned)(base + c4);
                #pragma unroll
                for (int n = 1; n < 8; ++n) {
                    const bool lt = acc[n][j] < ms;
                    ms = lt ? acc[n][j] : ms;
                    mc = lt ? (unsigned)(base + n * 16 + c4) : mc;
                }
                unsigned long long k0 = packkey(ms, mc);
                #pragma unroll
                for (int off = 1; off < 16; off <<= 1) {
                    const unsigned long long k2 = __shfl_xor(k0, off, 64);
                    if (k2 < k0) k0 = k2;
                }
                ckey[j] = k0;
                cm[j] = unpackf(k0);

                if (k0 < bkey[j]) {
                    if (c4 == 0 && unpackf(bkey[j]) <= cm[j] + THETA) {
                        const int p = atomicAdd(&ecnt[wv][tj], 1);
                        if (p < ECT)
                            elist[wv][tj][p] = (unsigned)(bkey[j] & 0xffffffffull);
                    }
                    bkey[j] = k0;
                } else {
                    if (c4 == 0 && cm[j] <= unpackf(bkey[j]) + THETA) {
                        const int p = atomicAdd(&ecnt[wv][tj], 1);
                        if (p < ECT)
                            elist[wv][tj][p] = (unsigned)(k0 & 0xffffffffull);
                    }
                }
            }

            #pragma unroll
            for (int n = 0; n < 8; ++n)
                #pragma unroll
                for (int j = 0; j < 4; ++j) {
                    const unsigned cand = (unsigned)(base + n * 16 + c4);
                    if (acc[n][j] <= cm[j] + THETA &&
                        packkey(acc[n][j], cand) != ckey[j]) {
                        const int tj = g * 4 + j;
                        const int p = atomicAdd(&ecnt[wv][tj], 1);
                        if (p < ECT) elist[wv][tj][p] = cand;
                    }
                }

            __syncthreads();   // all waves done reading buf[(ch+1)&1] (from ch-1)
            if (ch < 7) {
                _Float16* dstb = bstage[(ch + 1) & 1];
                #pragma unroll
                for (int i = 0; i < 16; ++i) {
                    const int e = tid + (i << 8);
                    const int ep = e ^ ((e >> 3) & 7);
                    *reinterpret_cast<int4*>(dstb + ep * 8) = gst[i];
                }
            }
            __syncthreads();   // staged tile visible for next iteration
        }

        // broadcast approx winner to owner lanes (token c4) — verbatim R6
        unsigned bc0 = (unsigned)(bkey[0] & 0xffffffffull);
        unsigned bc1 = (unsigned)(bkey[1] & 0xffffffffull);
        unsigned bc2 = (unsigned)(bkey[2] & 0xffffffffull);
        unsigned bc3 = (unsigned)(bkey[3] & 0xffffffffull);
        const int srcl = (c4 >> 2) << 4;
        const unsigned w0 = __shfl(bc0, srcl, 64);
        const unsigned w1 = __shfl(bc1, srcl, 64);
        const unsigned w2 = __shfl(bc2, srcl, 64);
        const unsigned w3 = __shfl(bc3, srcl, 64);
        const unsigned wa = (c4 & 1) ? w1 : w0;
        const unsigned wb = (c4 & 1) ? w3 : w2;
        const unsigned wincand = (c4 & 2) ? wb : wa;

        // ---- exact winner: 4-lane relay of R1's sequential 256-fmaf chain ----
        unsigned long long bestk;
        {
            const float* wp = cblf + (size_t)wincand * D_;
            float4 wA = *reinterpret_cast<const float4*>(wp + g * 8);
            float4 wB = *reinterpret_cast<const float4*>(wp + g * 8 + 4);
            float4 nA = *reinterpret_cast<const float4*>(wp + 32 + g * 8);
            float4 nB = *reinterpret_cast<const float4*>(wp + 32 + g * 8 + 4);
            float a0 = 0.0f;
            #pragma unroll
            for (int s = 0; s < 32; ++s) {
                const int kk = s >> 2;
                if ((s & 3) == g) {
                    a0 = fmaf(wA.x, r_[kk * 8 + 0], a0);
                    a0 = fmaf(wA.y, r_[kk * 8 + 1], a0);
                    a0 = fmaf(wA.z, r_[kk * 8 + 2], a0);
                    a0 = fmaf(wA.w, r_[kk * 8 + 3], a0);
                    a0 = fmaf(wB.x, r_[kk * 8 + 4], a0);
                    a0 = fmaf(wB.y, r_[kk * 8 + 5], a0);
                    a0 = fmaf(wB.z, r_[kk * 8 + 6], a0);
                    a0 = fmaf(wB.w, r_[kk * 8 + 7], a0);
                    wA = nA; wB = nB;
                    if (kk + 2 < 8) {
                        nA = *reinterpret_cast<const float4*>(wp + (kk + 2) * 32 + g * 8);
                        nB = *reinterpret_cast<const float4*>(wp + (kk + 2) * 32 + g * 8 + 4);
                    }
                }
                a0 = __shfl(a0, (lane + 48) & 63, 64);   // pass acc g -> g+1
            }
            a0 = __shfl(a0, c4, 64);                      // chain result at g=0 lane
            const float scw = __fadd_rn(__fsub_rn(rrv, __fmul_rn(2.0f, a0)), wwl[wincand]);
            bestk = packkey(scw, wincand);
        }

        // ---- extras: per-token serial, all 16 groups concurrent ----
        {
            const int myn = min(ecnt[wv][c4], ECT);
            #pragma unroll 1
            for (int i = 0; i < myn; ++i) {
                const unsigned ec = elist[wv][c4][i];
                const float* ep = cblf + (size_t)ec * D_;
                float4 wA = *reinterpret_cast<const float4*>(ep + g * 8);
                float4 wB = *reinterpret_cast<const float4*>(ep + g * 8 + 4);
                float4 nA = *reinterpret_cast<const float4*>(ep + 32 + g * 8);
                float4 nB = *reinterpret_cast<const float4*>(ep + 32 + g * 8 + 4);
                float q = 0.0f;
                #pragma unroll
                for (int s = 0; s < 32; ++s) {
                    const int kk = s >> 2;
                    if ((s & 3) == g) {
                        q = fmaf(wA.x, r_[kk * 8 + 0], q);
                        q = fmaf(wA.y, r_[kk * 8 + 1], q);
                        q = fmaf(wA.z, r_[kk * 8 + 2], q);
                        q = fmaf(wA.w, r_[kk * 8 + 3], q);
                        q = fmaf(wB.x, r_[kk * 8 + 4], q);
                        q = fmaf(wB.y, r_[kk * 8 + 5], q);
                        q = fmaf(wB.z, r_[kk * 8 + 6], q);
                        q = fmaf(wB.w, r_[kk * 8 + 7], q);
                        wA = nA; wB = nB;
                        if (kk + 2 < 8) {
                            nA = *reinterpret_cast<const float4*>(ep + (kk + 2) * 32 + g * 8);
                            nB = *reinterpret_cast<const float4*>(ep + (kk + 2) * 32 + g * 8 + 4);
                        }
                    }
                    q = __shfl(q, (lane + 48) & 63, 64);
                }
                q = __shfl(q, c4, 64);
                const float sce = __fadd_rn(__fsub_rn(rrv, __fmul_rn(2.0f, q)), wwl[ec]);
                const unsigned long long k2 = packkey(sce, ec);
                if (k2 < bestk) bestk = k2;
            }
        }

        const unsigned fc = (unsigned)(bestk & 0xffffffffull);
        if (g == 0)
            out[(size_t)B_ * D_ * T_ + ((size_t)b * L_ + l) * T_ + tl] = (float)fc;

        // ---- residual update (frozen element-wise f32) ----
        {
            const float* up = cblf + (size_t)fc * D_;
            #pragma unroll
            for (int kk = 0; kk < 8; ++kk) {
                const float4 ua = *reinterpret_cast<const float4*>(up + kk * 32 + g * 8);
                const float4 ub = *reinterpret_cast<const float4*>(up + kk * 32 + g * 8 + 4);
                r_[kk * 8 + 0] = __fsub_rn(r_[kk * 8 + 0], ua.x);
                r_[kk * 8 + 1] = __fsub_rn(r_[kk * 8 + 1], ua.y);
                r_[kk * 8 + 2] = __fsub_rn(r_[kk * 8 + 2], ua.z);
                r_[kk * 8 + 3] = __fsub_rn(r_[kk * 8 + 3], ua.w);
                r_[kk * 8 + 4] = __fsub_rn(r_[kk * 8 + 4], ub.x);
                r_[kk * 8 + 5] = __fsub_rn(r_[kk * 8 + 5], ub.y);
                r_[kk * 8 + 6] = __fsub_rn(r_[kk * 8 + 6], ub.z);
                r_[kk * 8 + 7] = __fsub_rn(r_[kk * 8 + 7], ub.w);
            }
        }
    }

    // epilogue (frozen): quantized = x - r_final
    #pragma unroll
    for (int kk = 0; kk < 8; ++kk)
        #pragma unroll
        for (int e = 0; e < 8; ++e) {
            const size_t gi = xbase + (size_t)(kk * 32 + g * 8 + e) * T_;
            out[gi] = __fsub_rn(x[gi], r_[kk * 8 + e]);
        }
}

extern "C" void kernel_launch(void* const* d_in, const int* in_sizes, int n_in,
                              void* d_out, int out_size, void* d_ws, size_t ws_size,
                              hipStream_t stream) {
    const float* x  = (const float*)d_in[0];
    const float* cb = (const float*)d_in[1];
    float* out = (float*)d_out;
    float*    ww   = (float*)d_ws;                       // 32 KB
    _Float16* cb16 = (_Float16*)((char*)d_ws + 32768);   // 4 MB

    hipLaunchKernelGGL(rvq_ww_kernel,  dim3((L_ * K_) / 4), dim3(256), 0, stream, cb, ww);
    hipLaunchKernelGGL(rvq_cvt_kernel, dim3((L_ * K_ * D_) / 2048), dim3(256), 0, stream, cb, cb16);
    hipLaunchKernelGGL(rvq_main_kernel, dim3((B_ * T_) / 64), dim3(256), 0, stream,
                       x, cb, cb16, ww, out);
}

// Round 8
// 992.906 us; speedup vs baseline: 1.3035x; 1.1106x over previous
//
#include <hip/hip_runtime.h>

#define D_ 256
#define T_ 2048
#define K_ 1024
#define L_ 8
#define B_ 16
#define THETA 0.5f
#define ECT 32

typedef _Float16 f16x8 __attribute__((ext_vector_type(8)));
typedef float    f32x4 __attribute__((ext_vector_type(4)));

__device__ __forceinline__ unsigned long long packkey(float sc, unsigned cand) {
    const unsigned fb = __float_as_uint(sc);
    const unsigned ob = fb ^ ((unsigned)((int)fb >> 31) | 0x80000000u);
    return (((unsigned long long)ob) << 32) | cand;
}
__device__ __forceinline__ float unpackf(unsigned long long key) {
    const unsigned ob = (unsigned)(key >> 32);
    const unsigned fb = (ob & 0x80000000u) ? (ob ^ 0x80000000u) : ~ob;
    return __uint_as_float(fb);
}

// ---------------------------------------------------------------------------
// Prep 1 (validated): ww[l*K + c] = ||codebook[l][c]||^2
// ---------------------------------------------------------------------------
__global__ __launch_bounds__(256, 4)
void rvq_ww_kernel(const float* __restrict__ cb, float* __restrict__ ww) {
    const int row  = blockIdx.x * 4 + (threadIdx.x >> 6);
    const int lane = threadIdx.x & 63;
    const float4 v = *reinterpret_cast<const float4*>(cb + (size_t)row * D_ + (lane << 2));
    float s = v.x * v.x + v.y * v.y + v.z * v.z + v.w * v.w;
    #pragma unroll
    for (int off = 1; off < 64; off <<= 1) s += __shfl_xor(s, off, 64);
    if (lane == 0) ww[row] = s;
}

// ---------------------------------------------------------------------------
// Prep 2: codebooks f32 -> f16 (linear layout)
// ---------------------------------------------------------------------------
__global__ __launch_bounds__(256)
void rvq_cvt_kernel(const float* __restrict__ cb, _Float16* __restrict__ cb16) {
    const int i = (blockIdx.x * 256 + threadIdx.x) * 8;
    const float4 a = *reinterpret_cast<const float4*>(cb + i);
    const float4 b = *reinterpret_cast<const float4*>(cb + i + 4);
    f16x8 v;
    v[0] = (_Float16)a.x; v[1] = (_Float16)a.y; v[2] = (_Float16)a.z; v[3] = (_Float16)a.w;
    v[4] = (_Float16)b.x; v[5] = (_Float16)b.y; v[6] = (_Float16)b.z; v[7] = (_Float16)b.w;
    *reinterpret_cast<f16x8*>(cb16 + i) = v;
}

// ---------------------------------------------------------------------------
// Main (R8): register residual; 2x32KB double-buffered LDS B (plain reg
// staging, no volatile asm); 16 chunks x 64 cands; cross-layer prefetch;
// 2 blocks/CU. Decision arithmetic frozen from R7 (passed).
// ---------------------------------------------------------------------------
__global__ __launch_bounds__(256, 2)
void rvq_main_kernel(const float* __restrict__ x, const float* __restrict__ cbf,
                     const _Float16* __restrict__ cb16, const float* __restrict__ ww,
                     float* __restrict__ out) {
    __shared__ __align__(16) _Float16 bstage[2][16384];   // 2 x 32 KB B tiles
    __shared__ unsigned elist[4][16][ECT];
    __shared__ int      ecnt[4][16];

    const int tid  = threadIdx.x;
    const int lane = tid & 63;
    const int wv   = tid >> 6;
    const int c4   = lane & 15;          // token within wave tile
    const int g    = lane >> 4;          // d-group
    const int tg   = blockIdx.x * 64 + wv * 16 + c4;
    const int b    = tg >> 11;
    const int tl   = tg & (T_ - 1);
    const size_t xbase = ((size_t)b << 19) + tl;

    // residual f32 in regs: r_[kk*8+e] = r[token c4][d = kk*32 + g*8 + e]
    float r_[64];
    #pragma unroll
    for (int kk = 0; kk < 8; ++kk)
        #pragma unroll
        for (int e = 0; e < 8; ++e)
            r_[kk * 8 + e] = x[xbase + (size_t)(kk * 32 + g * 8 + e) * T_];

    // swizzled LDS read offset (granule units): lp2 = (4*c4+g) ^ (c4>>1)
    const int lp2 = ((c4 << 2) | g) ^ ((c4 >> 1) & 7);

    // ---- prologue: stage layer-0 chunk-0 into buf0 ----
    {
        int4 gst[8];
        #pragma unroll
        for (int i = 0; i < 8; ++i) {
            const int e = tid + (i << 8);
            const int eg = e & 3, ec = (e >> 2) & 15, en = (e >> 6) & 3, ek = (e >> 8) & 7;
            gst[i] = *reinterpret_cast<const int4*>(
                cb16 + (size_t)(en * 16 + ec) * D_ + ek * 32 + eg * 8);
        }
        #pragma unroll
        for (int i = 0; i < 8; ++i) {
            const int e = tid + (i << 8);
            const int ep = e ^ ((e >> 3) & 7);
            *reinterpret_cast<int4*>(&bstage[0][ep * 8]) = gst[i];
        }
    }
    __syncthreads();

    #pragma unroll 1
    for (int l = 0; l < L_; ++l) {
        const _Float16* __restrict__ cbl6 = cb16 + (size_t)l * K_ * D_;
        const float*    __restrict__ cblf = cbf  + (size_t)l * K_ * D_;
        const float*    __restrict__ wwl  = ww + l * K_;

        if (lane < 16) ecnt[wv][lane] = 0;

        // ---- rr: bitwise-equivalent reconstruction of R1's butterfly ----
        float rrv;
        {
            float Tk[8];
            #pragma unroll
            for (int kk = 0; kk < 8; ++kk) {
                float4 v;
                v.x = r_[kk * 8 + 0]; v.y = r_[kk * 8 + 1];
                v.z = r_[kk * 8 + 2]; v.w = r_[kk * 8 + 3];
                float s = v.x * v.x + v.y * v.y + v.z * v.z + v.w * v.w;
                float4 u;
                u.x = r_[kk * 8 + 4]; u.y = r_[kk * 8 + 5];
                u.z = r_[kk * 8 + 6]; u.w = r_[kk * 8 + 7];
                float s2 = u.x * u.x + u.y * u.y + u.z * u.z + u.w * u.w;
                const float p  = s + s2;
                const float po = __shfl_xor(p, 16, 64);
                const float q  = p + po;
                const float qo = __shfl_xor(q, 32, 64);
                Tk[kk] = q + qo;
            }
            const float u01 = Tk[0] + Tk[1], u23 = Tk[2] + Tk[3];
            const float u45 = Tk[4] + Tk[5], u67 = Tk[6] + Tk[7];
            rrv = (u01 + u23) + (u45 + u67);
        }

        // f16 A-fragments from register residual
        f16x8 fr[8];
        #pragma unroll
        for (int kk = 0; kk < 8; ++kk)
            #pragma unroll
            for (int e = 0; e < 8; ++e)
                fr[kk][e] = (_Float16)r_[kk * 8 + e];

        unsigned long long bkey[4];
        #pragma unroll
        for (int j = 0; j < 4; ++j) bkey[j] = packkey(__builtin_inff(), 0u);

        // ---- screen: 16 chunks x 64 cands; B from LDS double buffer ----
        #pragma unroll 1
        for (int ch = 0; ch < 16; ++ch) {
            const bool do_pref = (ch < 15) || (l < L_ - 1);
            const _Float16* psrc = (ch < 15) ? cbl6 : (cbl6 + (size_t)K_ * D_);
            const int pbase = (ch < 15) ? (ch + 1) * 64 : 0;

            int4 gst[8];
            if (do_pref) {
                #pragma unroll
                for (int i = 0; i < 8; ++i) {
                    const int e = tid + (i << 8);
                    const int eg = e & 3, ec = (e >> 2) & 15, en = (e >> 6) & 3, ek = (e >> 8) & 7;
                    gst[i] = *reinterpret_cast<const int4*>(
                        psrc + (size_t)(pbase + en * 16 + ec) * D_ + ek * 32 + eg * 8);
                }
            }

            const int base = ch * 64;
            const _Float16* bufp = bstage[ch & 1];
            f32x4 acc[4];
            #pragma unroll
            for (int n = 0; n < 4; ++n) acc[n] = (f32x4){0.f, 0.f, 0.f, 0.f};

            #pragma unroll
            for (int kk = 0; kk < 8; ++kk) {
                f16x8 bfv[4];
                #pragma unroll
                for (int n = 0; n < 4; ++n)
                    bfv[n] = *reinterpret_cast<const f16x8*>(
                        bufp + (size_t)(((kk * 4 + n) * 64 + lp2) * 8));
                #pragma unroll
                for (int n = 0; n < 4; ++n)
                    acc[n] = __builtin_amdgcn_mfma_f32_16x16x32_f16(fr[kk], bfv[n], acc[n], 0, 0, 0);
            }

            float wwv[4];
            #pragma unroll
            for (int n = 0; n < 4; ++n) wwv[n] = wwl[base + n * 16 + c4];
            #pragma unroll
            for (int n = 0; n < 4; ++n)
                #pragma unroll
                for (int j = 0; j < 4; ++j)
                    acc[n][j] = fmaf(-2.0f, acc[n][j], wwv[n]);   // screen score

            unsigned long long ckey[4];
            float cm[4];
            #pragma unroll
            for (int j = 0; j < 4; ++j) {
                const int tj = g * 4 + j;            // token of this acc row
                float ms = acc[0][j];
                unsigned mc = (unsigned)(base + c4);
                #pragma unroll
                for (int n = 1; n < 4; ++n) {
                    const bool lt = acc[n][j] < ms;
                    ms = lt ? acc[n][j] : ms;
                    mc = lt ? (unsigned)(base + n * 16 + c4) : mc;
                }
                unsigned long long k0 = packkey(ms, mc);
                #pragma unroll
                for (int off = 1; off < 16; off <<= 1) {
                    const unsigned long long k2 = __shfl_xor(k0, off, 64);
                    if (k2 < k0) k0 = k2;
                }
                ckey[j] = k0;
                cm[j] = unpackf(k0);

                if (k0 < bkey[j]) {
                    if (c4 == 0 && unpackf(bkey[j]) <= cm[j] + THETA) {
                        const int p = atomicAdd(&ecnt[wv][tj], 1);
                        if (p < ECT)
                            elist[wv][tj][p] = (unsigned)(bkey[j] & 0xffffffffull);
                    }
                    bkey[j] = k0;
                } else {
                    if (c4 == 0 && cm[j] <= unpackf(bkey[j]) + THETA) {
                        const int p = atomicAdd(&ecnt[wv][tj], 1);
                        if (p < ECT)
                            elist[wv][tj][p] = (unsigned)(k0 & 0xffffffffull);
                    }
                }
            }

            #pragma unroll
            for (int n = 0; n < 4; ++n)
                #pragma unroll
                for (int j = 0; j < 4; ++j) {
                    const unsigned cand = (unsigned)(base + n * 16 + c4);
                    if (acc[n][j] <= cm[j] + THETA &&
                        packkey(acc[n][j], cand) != ckey[j]) {
                        const int tj = g * 4 + j;
                        const int p = atomicAdd(&ecnt[wv][tj], 1);
                        if (p < ECT) elist[wv][tj][p] = cand;
                    }
                }

            __syncthreads();   // all waves done reading buf[(ch+1)&1]
            if (do_pref) {
                _Float16* dstb = bstage[(ch + 1) & 1];
                #pragma unroll
                for (int i = 0; i < 8; ++i) {
                    const int e = tid + (i << 8);
                    const int ep = e ^ ((e >> 3) & 7);
                    *reinterpret_cast<int4*>(dstb + ep * 8) = gst[i];
                }
            }
            __syncthreads();   // staged tile visible
        }

        // broadcast approx winner to owner lanes (token c4) — frozen
        unsigned bc0 = (unsigned)(bkey[0] & 0xffffffffull);
        unsigned bc1 = (unsigned)(bkey[1] & 0xffffffffull);
        unsigned bc2 = (unsigned)(bkey[2] & 0xffffffffull);
        unsigned bc3 = (unsigned)(bkey[3] & 0xffffffffull);
        const int srcl = (c4 >> 2) << 4;
        const unsigned w0 = __shfl(bc0, srcl, 64);
        const unsigned w1 = __shfl(bc1, srcl, 64);
        const unsigned w2 = __shfl(bc2, srcl, 64);
        const unsigned w3 = __shfl(bc3, srcl, 64);
        const unsigned wa = (c4 & 1) ? w1 : w0;
        const unsigned wb = (c4 & 1) ? w3 : w2;
        const unsigned wincand = (c4 & 2) ? wb : wa;

        // ---- exact winner: 4-lane relay of R1's sequential 256-fmaf chain ----
        unsigned long long bestk;
        {
            const float* wp = cblf + (size_t)wincand * D_;
            float4 wA = *reinterpret_cast<const float4*>(wp + g * 8);
            float4 wB = *reinterpret_cast<const float4*>(wp + g * 8 + 4);
            float4 nA = *reinterpret_cast<const float4*>(wp + 32 + g * 8);
            float4 nB = *reinterpret_cast<const float4*>(wp + 32 + g * 8 + 4);
            float a0 = 0.0f;
            #pragma unroll
            for (int s = 0; s < 32; ++s) {
                const int kk = s >> 2;
                if ((s & 3) == g) {
                    a0 = fmaf(wA.x, r_[kk * 8 + 0], a0);
                    a0 = fmaf(wA.y, r_[kk * 8 + 1], a0);
                    a0 = fmaf(wA.z, r_[kk * 8 + 2], a0);
                    a0 = fmaf(wA.w, r_[kk * 8 + 3], a0);
                    a0 = fmaf(wB.x, r_[kk * 8 + 4], a0);
                    a0 = fmaf(wB.y, r_[kk * 8 + 5], a0);
                    a0 = fmaf(wB.z, r_[kk * 8 + 6], a0);
                    a0 = fmaf(wB.w, r_[kk * 8 + 7], a0);
                    wA = nA; wB = nB;
                    if (kk + 2 < 8) {
                        nA = *reinterpret_cast<const float4*>(wp + (kk + 2) * 32 + g * 8);
                        nB = *reinterpret_cast<const float4*>(wp + (kk + 2) * 32 + g * 8 + 4);
                    }
                }
                a0 = __shfl(a0, (lane + 48) & 63, 64);   // pass acc g -> g+1
            }
            a0 = __shfl(a0, c4, 64);                      // chain result to owners
            const float scw = __fadd_rn(__fsub_rn(rrv, __fmul_rn(2.0f, a0)), wwl[wincand]);
            bestk = packkey(scw, wincand);
        }

        // ---- extras: per-token serial, all 16 groups concurrent ----
        {
            const int myn = min(ecnt[wv][c4], ECT);
            #pragma unroll 1
            for (int i = 0; i < myn; ++i) {
                const unsigned ec = elist[wv][c4][i];
                const float* ep = cblf + (size_t)ec * D_;
                float4 wA = *reinterpret_cast<const float4*>(ep + g * 8);
                float4 wB = *reinterpret_cast<const float4*>(ep + g * 8 + 4);
                float4 nA = *reinterpret_cast<const float4*>(ep + 32 + g * 8);
                float4 nB = *reinterpret_cast<const float4*>(ep + 32 + g * 8 + 4);
                float q = 0.0f;
                #pragma unroll
                for (int s = 0; s < 32; ++s) {
                    const int kk = s >> 2;
                    if ((s & 3) == g) {
                        q = fmaf(wA.x, r_[kk * 8 + 0], q);
                        q = fmaf(wA.y, r_[kk * 8 + 1], q);
                        q = fmaf(wA.z, r_[kk * 8 + 2], q);
                        q = fmaf(wA.w, r_[kk * 8 + 3], q);
                        q = fmaf(wB.x, r_[kk * 8 + 4], q);
                        q = fmaf(wB.y, r_[kk * 8 + 5], q);
                        q = fmaf(wB.z, r_[kk * 8 + 6], q);
                        q = fmaf(wB.w, r_[kk * 8 + 7], q);
                        wA = nA; wB = nB;
                        if (kk + 2 < 8) {
                            nA = *reinterpret_cast<const float4*>(ep + (kk + 2) * 32 + g * 8);
                            nB = *reinterpret_cast<const float4*>(ep + (kk + 2) * 32 + g * 8 + 4);
                        }
                    }
                    q = __shfl(q, (lane + 48) & 63, 64);
                }
                q = __shfl(q, c4, 64);
                const float sce = __fadd_rn(__fsub_rn(rrv, __fmul_rn(2.0f, q)), wwl[ec]);
                const unsigned long long k2 = packkey(sce, ec);
                if (k2 < bestk) bestk = k2;
            }
        }

        const unsigned fc = (unsigned)(bestk & 0xffffffffull);
        if (g == 0)
            out[(size_t)B_ * D_ * T_ + ((size_t)b * L_ + l) * T_ + tl] = (float)fc;

        // ---- residual update (frozen element-wise f32) ----
        {
            const float* up = cblf + (size_t)fc * D_;
            #pragma unroll
            for (int kk = 0; kk < 8; ++kk) {
                const float4 ua = *reinterpret_cast<const float4*>(up + kk * 32 + g * 8);
                const float4 ub = *reinterpret_cast<const float4*>(up + kk * 32 + g * 8 + 4);
                r_[kk * 8 + 0] = __fsub_rn(r_[kk * 8 + 0], ua.x);
                r_[kk * 8 + 1] = __fsub_rn(r_[kk * 8 + 1], ua.y);
                r_[kk * 8 + 2] = __fsub_rn(r_[kk * 8 + 2], ua.z);
                r_[kk * 8 + 3] = __fsub_rn(r_[kk * 8 + 3], ua.w);
                r_[kk * 8 + 4] = __fsub_rn(r_[kk * 8 + 4], ub.x);
                r_[kk * 8 + 5] = __fsub_rn(r_[kk * 8 + 5], ub.y);
                r_[kk * 8 + 6] = __fsub_rn(r_[kk * 8 + 6], ub.z);
                r_[kk * 8 + 7] = __fsub_rn(r_[kk * 8 + 7], ub.w);
            }
        }
    }

    // epilogue (frozen): quantized = x - r_final
    #pragma unroll
    for (int kk = 0; kk < 8; ++kk)
        #pragma unroll
        for (int e = 0; e < 8; ++e) {
            const size_t gi = xbase + (size_t)(kk * 32 + g * 8 + e) * T_;
            out[gi] = __fsub_rn(x[gi], r_[kk * 8 + e]);
        }
}

extern "C" void kernel_launch(void* const* d_in, const int* in_sizes, int n_in,
                              void* d_out, int out_size, void* d_ws, size_t ws_size,
                              hipStream_t stream) {
    const float* x  = (const float*)d_in[0];
    const float* cb = (const float*)d_in[1];
    float* out = (float*)d_out;
    float*    ww   = (float*)d_ws;                       // 32 KB
    _Float16* cb16 = (_Float16*)((char*)d_ws + 32768);   // 4 MB

    hipLaunchKernelGGL(rvq_ww_kernel,  dim3((L_ * K_) / 4), dim3(256), 0, stream, cb, ww);
    hipLaunchKernelGGL(rvq_cvt_kernel, dim3((L_ * K_ * D_) / 2048), dim3(256), 0, stream, cb, cb16);
    hipLaunchKernelGGL(rvq_main_kernel, dim3((B_ * T_) / 64), dim3(256), 0, stream,
                       x, cb, cb16, ww, out);
}

// Round 9
// 845.155 us; speedup vs baseline: 1.5314x; 1.1748x over previous
//
#include <hip/hip_runtime.h>

#define D_ 256
#define T_ 2048
#define K_ 1024
#define L_ 8
#define B_ 16
#define THETA 0.5f
#define ECT 24

typedef _Float16 f16x8 __attribute__((ext_vector_type(8)));
typedef float    f32x4 __attribute__((ext_vector_type(4)));

typedef const __attribute__((address_space(1))) unsigned int* gas1_t;
typedef __attribute__((address_space(3))) unsigned int*       las3_t;

__device__ __forceinline__ void gls16(const void* g, void* l) {
    __builtin_amdgcn_global_load_lds((gas1_t)g, (las3_t)l, 16, 0, 0);
}

__device__ __forceinline__ unsigned long long packkey(float sc, unsigned cand) {
    const unsigned fb = __float_as_uint(sc);
    const unsigned ob = fb ^ ((unsigned)((int)fb >> 31) | 0x80000000u);
    return (((unsigned long long)ob) << 32) | cand;
}
__device__ __forceinline__ float unpackf(unsigned long long key) {
    const unsigned ob = (unsigned)(key >> 32);
    const unsigned fb = (ob & 0x80000000u) ? (ob ^ 0x80000000u) : ~ob;
    return __uint_as_float(fb);
}

// ---------------------------------------------------------------------------
// Prep 1 (frozen): ww[l*K + c] = ||codebook[l][c]||^2
// ---------------------------------------------------------------------------
__global__ __launch_bounds__(256, 4)
void rvq_ww_kernel(const float* __restrict__ cb, float* __restrict__ ww) {
    const int row  = blockIdx.x * 4 + (threadIdx.x >> 6);
    const int lane = threadIdx.x & 63;
    const float4 v = *reinterpret_cast<const float4*>(cb + (size_t)row * D_ + (lane << 2));
    float s = v.x * v.x + v.y * v.y + v.z * v.z + v.w * v.w;
    #pragma unroll
    for (int off = 1; off < 64; off <<= 1) s += __shfl_xor(s, off, 64);
    if (lane == 0) ww[row] = s;
}

// ---------------------------------------------------------------------------
// Prep 2: codebooks f32 -> f16 in LDS-IMAGE order.
// Entry e: lane=e&63, sub=(e>>6)&15, ch=(e>>10)&31, l=e>>15;
// n=sub&1, kk=sub>>1, g=lane>>4, c4=lane&15.
// content = cb[l][ch*32 + n*16 + c4][kk*32 + g*8 .. +8]  (RN conversion)
// ---------------------------------------------------------------------------
__global__ __launch_bounds__(256)
void rvq_cvtp_kernel(const float* __restrict__ cb, _Float16* __restrict__ cbp) {
    const int e    = blockIdx.x * 256 + threadIdx.x;
    const int lane = e & 63, sub = (e >> 6) & 15, ch = (e >> 10) & 31, l = e >> 15;
    const int n = sub & 1, kk = sub >> 1, g = lane >> 4, c4 = lane & 15;
    const float* src = cb + (size_t)(l * 1024 + ch * 32 + n * 16 + c4) * D_ + kk * 32 + g * 8;
    const float4 a = *reinterpret_cast<const float4*>(src);
    const float4 b = *reinterpret_cast<const float4*>(src + 4);
    f16x8 v;
    v[0] = (_Float16)a.x; v[1] = (_Float16)a.y; v[2] = (_Float16)a.z; v[3] = (_Float16)a.w;
    v[4] = (_Float16)b.x; v[5] = (_Float16)b.y; v[6] = (_Float16)b.z; v[7] = (_Float16)b.w;
    *reinterpret_cast<f16x8*>(cbp + (size_t)e * 8) = v;
}

// ---------------------------------------------------------------------------
// Main (R9): register residual; async global_load_lds double-buffered B
// (pre-permuted, conflict-free, zero staging VGPR); 32 chunks x 32 cands;
// running-best in LDS bmink. Decision arithmetic frozen from R8 (passed).
// ---------------------------------------------------------------------------
__global__ __launch_bounds__(256, 2)
void rvq_main_kernel(const float* __restrict__ x, const float* __restrict__ cbf,
                     const _Float16* __restrict__ cb16p, const float* __restrict__ ww,
                     float* __restrict__ out) {
    __shared__ __align__(16) _Float16 bstage[2][8192];    // 2 x 16 KB tiles
    __shared__ unsigned long long bmink[64];
    __shared__ unsigned short elist[4][16][ECT];
    __shared__ int ecnt[4][16];

    const int tid  = threadIdx.x;
    const int lane = tid & 63;
    const int wv   = tid >> 6;
    const int c4   = lane & 15;          // token within wave tile
    const int g    = lane >> 4;          // d-group
    const int trow = wv * 16 + c4;
    const int tg   = blockIdx.x * 64 + trow;
    const int b    = tg >> 11;
    const int tl   = tg & (T_ - 1);
    const size_t xbase = ((size_t)b << 19) + tl;

    // residual f32 in regs: r_[kk*8+e] = r[token c4][d = kk*32 + g*8 + e]
    float r_[64];
    #pragma unroll
    for (int kk = 0; kk < 8; ++kk)
        #pragma unroll
        for (int e = 0; e < 8; ++e)
            r_[kk * 8 + e] = x[xbase + (size_t)(kk * 32 + g * 8 + e) * T_];

    // ---- prologue: stage layer-0 chunk-0 into buf0 (async DMA) ----
    {
        const _Float16* srcb = cb16p + (size_t)(wv * 256 + lane) * 8;
        _Float16* dstb = &bstage[0][wv * 256 * 8];
        #pragma unroll
        for (int i = 0; i < 4; ++i)
            gls16(srcb + i * 512, dstb + i * 512);
        asm volatile("s_waitcnt vmcnt(0)" ::: "memory");
    }
    __syncthreads();

    #pragma unroll 1
    for (int l = 0; l < L_; ++l) {
        const float* __restrict__ cblf = cbf + (size_t)l * K_ * D_;
        const float* __restrict__ wwl  = ww + l * K_;

        if (lane < 16) { ecnt[wv][lane] = 0; bmink[wv * 16 + lane] = ~0ull; }

        // ---- rr (frozen bitwise tree) ----
        float rrv;
        {
            float Tk[8];
            #pragma unroll
            for (int kk = 0; kk < 8; ++kk) {
                float4 v;
                v.x = r_[kk * 8 + 0]; v.y = r_[kk * 8 + 1];
                v.z = r_[kk * 8 + 2]; v.w = r_[kk * 8 + 3];
                float s = v.x * v.x + v.y * v.y + v.z * v.z + v.w * v.w;
                float4 u;
                u.x = r_[kk * 8 + 4]; u.y = r_[kk * 8 + 5];
                u.z = r_[kk * 8 + 6]; u.w = r_[kk * 8 + 7];
                float s2 = u.x * u.x + u.y * u.y + u.z * u.z + u.w * u.w;
                const float p  = s + s2;
                const float po = __shfl_xor(p, 16, 64);
                const float q  = p + po;
                const float qo = __shfl_xor(q, 32, 64);
                Tk[kk] = q + qo;
            }
            const float u01 = Tk[0] + Tk[1], u23 = Tk[2] + Tk[3];
            const float u45 = Tk[4] + Tk[5], u67 = Tk[6] + Tk[7];
            rrv = (u01 + u23) + (u45 + u67);
        }

        // f16 A-fragments (frozen values)
        f16x8 fr[8];
        #pragma unroll
        for (int kk = 0; kk < 8; ++kk)
            #pragma unroll
            for (int e = 0; e < 8; ++e)
                fr[kk][e] = (_Float16)r_[kk * 8 + e];

        // ---- screen: 32 chunks x 32 cands ----
        #pragma unroll 1
        for (int ch = 0; ch < 32; ++ch) {
            // issue async stage of the next tile (cross-layer at ch==31)
            if ((ch < 31) || (l < L_ - 1)) {
                const size_t E0n = (size_t)(l * 32 + ch + 1) * 1024;
                const _Float16* srcb = cb16p + (E0n + wv * 256 + lane) * 8;
                _Float16* dstb = &bstage[(ch + 1) & 1][wv * 256 * 8];
                #pragma unroll
                for (int i = 0; i < 4; ++i)
                    gls16(srcb + i * 512, dstb + i * 512);
            }

            const int base = ch * 32;
            const _Float16* bufp = bstage[ch & 1];
            f32x4 acc[2];
            acc[0] = (f32x4){0.f, 0.f, 0.f, 0.f};
            acc[1] = (f32x4){0.f, 0.f, 0.f, 0.f};

            #pragma unroll
            for (int kk = 0; kk < 8; ++kk) {
                const f16x8 b0 = *reinterpret_cast<const f16x8*>(
                    bufp + ((kk * 2 + 0) * 64 + lane) * 8);
                const f16x8 b1 = *reinterpret_cast<const f16x8*>(
                    bufp + ((kk * 2 + 1) * 64 + lane) * 8);
                acc[0] = __builtin_amdgcn_mfma_f32_16x16x32_f16(fr[kk], b0, acc[0], 0, 0, 0);
                acc[1] = __builtin_amdgcn_mfma_f32_16x16x32_f16(fr[kk], b1, acc[1], 0, 0, 0);
            }

            float wwv[2];
            #pragma unroll
            for (int n = 0; n < 2; ++n) wwv[n] = wwl[base + n * 16 + c4];
            #pragma unroll
            for (int n = 0; n < 2; ++n)
                #pragma unroll
                for (int j = 0; j < 4; ++j)
                    acc[n][j] = fmaf(-2.0f, acc[n][j], wwv[n]);   // screen score

            unsigned long long ckey[4];
            float cm[4];
            #pragma unroll
            for (int j = 0; j < 4; ++j) {
                const int tj = g * 4 + j;
                float ms = acc[0][j];
                unsigned mc = (unsigned)(base + c4);
                {
                    const bool lt = acc[1][j] < ms;
                    ms = lt ? acc[1][j] : ms;
                    mc = lt ? (unsigned)(base + 16 + c4) : mc;
                }
                unsigned long long k0 = packkey(ms, mc);
                #pragma unroll
                for (int off = 1; off < 16; off <<= 1) {
                    const unsigned long long k2 = __shfl_xor(k0, off, 64);
                    if (k2 < k0) k0 = k2;
                }
                ckey[j] = k0;
                cm[j] = unpackf(k0);

                if (c4 == 0) {   // single writer for token tj (frozen semantics)
                    const unsigned long long old = bmink[wv * 16 + tj];
                    if (k0 < old) {
                        if (unpackf(old) <= cm[j] + THETA) {
                            const int p = atomicAdd(&ecnt[wv][tj], 1);
                            if (p < ECT)
                                elist[wv][tj][p] = (unsigned short)(old & 0xffffull);
                        }
                        bmink[wv * 16 + tj] = k0;
                    } else {
                        if (cm[j] <= unpackf(old) + THETA) {
                            const int p = atomicAdd(&ecnt[wv][tj], 1);
                            if (p < ECT)
                                elist[wv][tj][p] = (unsigned short)(k0 & 0xffffull);
                        }
                    }
                }
            }

            #pragma unroll
            for (int n = 0; n < 2; ++n)
                #pragma unroll
                for (int j = 0; j < 4; ++j) {
                    const unsigned cand = (unsigned)(base + n * 16 + c4);
                    if (acc[n][j] <= cm[j] + THETA &&
                        packkey(acc[n][j], cand) != ckey[j]) {
                        const int tj = g * 4 + j;
                        const int p = atomicAdd(&ecnt[wv][tj], 1);
                        if (p < ECT) elist[wv][tj][p] = (unsigned short)cand;
                    }
                }

            asm volatile("s_waitcnt vmcnt(0)" ::: "memory");   // DMA drained
            __syncthreads();                                    // tile visible
        }

        // approx winner from LDS (all 4 lanes of token read same)
        const unsigned wincand = (unsigned)(bmink[trow] & 0xffffffffull);

        // ---- exact winner: 4-lane relay of R1's sequential 256-fmaf chain ----
        unsigned long long bestk;
        {
            const float* wp = cblf + (size_t)wincand * D_;
            float4 wA = *reinterpret_cast<const float4*>(wp + g * 8);
            float4 wB = *reinterpret_cast<const float4*>(wp + g * 8 + 4);
            float4 nA = *reinterpret_cast<const float4*>(wp + 32 + g * 8);
            float4 nB = *reinterpret_cast<const float4*>(wp + 32 + g * 8 + 4);
            float a0 = 0.0f;
            #pragma unroll
            for (int s = 0; s < 32; ++s) {
                const int kk = s >> 2;
                if ((s & 3) == g) {
                    a0 = fmaf(wA.x, r_[kk * 8 + 0], a0);
                    a0 = fmaf(wA.y, r_[kk * 8 + 1], a0);
                    a0 = fmaf(wA.z, r_[kk * 8 + 2], a0);
                    a0 = fmaf(wA.w, r_[kk * 8 + 3], a0);
                    a0 = fmaf(wB.x, r_[kk * 8 + 4], a0);
                    a0 = fmaf(wB.y, r_[kk * 8 + 5], a0);
                    a0 = fmaf(wB.z, r_[kk * 8 + 6], a0);
                    a0 = fmaf(wB.w, r_[kk * 8 + 7], a0);
                    wA = nA; wB = nB;
                    if (kk + 2 < 8) {
                        nA = *reinterpret_cast<const float4*>(wp + (kk + 2) * 32 + g * 8);
                        nB = *reinterpret_cast<const float4*>(wp + (kk + 2) * 32 + g * 8 + 4);
                    }
                }
                a0 = __shfl(a0, (lane + 48) & 63, 64);
            }
            a0 = __shfl(a0, c4, 64);
            const float scw = __fadd_rn(__fsub_rn(rrv, __fmul_rn(2.0f, a0)), wwl[wincand]);
            bestk = packkey(scw, wincand);
        }

        // ---- extras: per-token serial, 16 groups concurrent (frozen) ----
        {
            const int myn = min(ecnt[wv][c4], ECT);
            #pragma unroll 1
            for (int i = 0; i < myn; ++i) {
                const unsigned ec = (unsigned)elist[wv][c4][i];
                const float* ep = cblf + (size_t)ec * D_;
                float4 wA = *reinterpret_cast<const float4*>(ep + g * 8);
                float4 wB = *reinterpret_cast<const float4*>(ep + g * 8 + 4);
                float4 nA = *reinterpret_cast<const float4*>(ep + 32 + g * 8);
                float4 nB = *reinterpret_cast<const float4*>(ep + 32 + g * 8 + 4);
                float q = 0.0f;
                #pragma unroll
                for (int s = 0; s < 32; ++s) {
                    const int kk = s >> 2;
                    if ((s & 3) == g) {
                        q = fmaf(wA.x, r_[kk * 8 + 0], q);
                        q = fmaf(wA.y, r_[kk * 8 + 1], q);
                        q = fmaf(wA.z, r_[kk * 8 + 2], q);
                        q = fmaf(wA.w, r_[kk * 8 + 3], q);
                        q = fmaf(wB.x, r_[kk * 8 + 4], q);
                        q = fmaf(wB.y, r_[kk * 8 + 5], q);
                        q = fmaf(wB.z, r_[kk * 8 + 6], q);
                        q = fmaf(wB.w, r_[kk * 8 + 7], q);
                        wA = nA; wB = nB;
                        if (kk + 2 < 8) {
                            nA = *reinterpret_cast<const float4*>(ep + (kk + 2) * 32 + g * 8);
                            nB = *reinterpret_cast<const float4*>(ep + (kk + 2) * 32 + g * 8 + 4);
                        }
                    }
                    q = __shfl(q, (lane + 48) & 63, 64);
                }
                q = __shfl(q, c4, 64);
                const float sce = __fadd_rn(__fsub_rn(rrv, __fmul_rn(2.0f, q)), wwl[ec]);
                const unsigned long long k2 = packkey(sce, ec);
                if (k2 < bestk) bestk = k2;
            }
        }

        const unsigned fc = (unsigned)(bestk & 0xffffffffull);
        if (g == 0)
            out[(size_t)B_ * D_ * T_ + ((size_t)b * L_ + l) * T_ + tl] = (float)fc;

        // ---- residual update (frozen element-wise f32) ----
        {
            const float* up = cblf + (size_t)fc * D_;
            #pragma unroll
            for (int kk = 0; kk < 8; ++kk) {
                const float4 ua = *reinterpret_cast<const float4*>(up + kk * 32 + g * 8);
                const float4 ub = *reinterpret_cast<const float4*>(up + kk * 32 + g * 8 + 4);
                r_[kk * 8 + 0] = __fsub_rn(r_[kk * 8 + 0], ua.x);
                r_[kk * 8 + 1] = __fsub_rn(r_[kk * 8 + 1], ua.y);
                r_[kk * 8 + 2] = __fsub_rn(r_[kk * 8 + 2], ua.z);
                r_[kk * 8 + 3] = __fsub_rn(r_[kk * 8 + 3], ua.w);
                r_[kk * 8 + 4] = __fsub_rn(r_[kk * 8 + 4], ub.x);
                r_[kk * 8 + 5] = __fsub_rn(r_[kk * 8 + 5], ub.y);
                r_[kk * 8 + 6] = __fsub_rn(r_[kk * 8 + 6], ub.z);
                r_[kk * 8 + 7] = __fsub_rn(r_[kk * 8 + 7], ub.w);
            }
        }
    }

    // epilogue (frozen): quantized = x - r_final
    #pragma unroll
    for (int kk = 0; kk < 8; ++kk)
        #pragma unroll
        for (int e = 0; e < 8; ++e) {
            const size_t gi = xbase + (size_t)(kk * 32 + g * 8 + e) * T_;
            out[gi] = __fsub_rn(x[gi], r_[kk * 8 + e]);
        }
}

extern "C" void kernel_launch(void* const* d_in, const int* in_sizes, int n_in,
                              void* d_out, int out_size, void* d_ws, size_t ws_size,
                              hipStream_t stream) {
    const float* x  = (const float*)d_in[0];
    const float* cb = (const float*)d_in[1];
    float* out = (float*)d_out;
    float*    ww    = (float*)d_ws;                       // 32 KB
    _Float16* cb16p = (_Float16*)((char*)d_ws + 32768);   // 4 MB (permuted)

    hipLaunchKernelGGL(rvq_ww_kernel,   dim3((L_ * K_) / 4), dim3(256), 0, stream, cb, ww);
    hipLaunchKernelGGL(rvq_cvtp_kernel, dim3(1024), dim3(256), 0, stream, cb, cb16p);
    hipLaunchKernelGGL(rvq_main_kernel, dim3((B_ * T_) / 64), dim3(256), 0, stream,
                       x, cb, cb16p, ww, out);
}

// Round 10
// 558.541 us; speedup vs baseline: 2.3172x; 1.5131x over previous
//
#include <hip/hip_runtime.h>

#define D_ 256
#define T_ 2048
#define K_ 1024
#define L_ 8
#define B_ 16
#define THETA 0.5f
#define ECT 40

typedef _Float16 f16x8 __attribute__((ext_vector_type(8)));
typedef float    f32x4 __attribute__((ext_vector_type(4)));

typedef const __attribute__((address_space(1))) unsigned int* gas1_t;
typedef __attribute__((address_space(3))) unsigned int*       las3_t;

__device__ __forceinline__ void gls16(const void* g, void* l) {
    __builtin_amdgcn_global_load_lds((gas1_t)g, (las3_t)l, 16, 0, 0);
}

__device__ __forceinline__ unsigned long long packkey(float sc, unsigned cand) {
    const unsigned fb = __float_as_uint(sc);
    const unsigned ob = fb ^ ((unsigned)((int)fb >> 31) | 0x80000000u);
    return (((unsigned long long)ob) << 32) | cand;
}
__device__ __forceinline__ float unpackf(unsigned long long key) {
    const unsigned ob = (unsigned)(key >> 32);
    const unsigned fb = (ob & 0x80000000u) ? (ob ^ 0x80000000u) : ~ob;
    return __uint_as_float(fb);
}
__device__ __forceinline__ unsigned short f2h_bits(float s) {
    union { _Float16 f; unsigned short u; } cv; cv.f = (_Float16)s; return cv.u;
}
__device__ __forceinline__ float h_bits2f(unsigned short u) {
    union { _Float16 f; unsigned short u; } cv; cv.u = u; return (float)cv.f;
}

// ---------------------------------------------------------------------------
// Prep 1 (frozen): ww[l*K + c] = ||codebook[l][c]||^2
// ---------------------------------------------------------------------------
__global__ __launch_bounds__(256, 4)
void rvq_ww_kernel(const float* __restrict__ cb, float* __restrict__ ww) {
    const int row  = blockIdx.x * 4 + (threadIdx.x >> 6);
    const int lane = threadIdx.x & 63;
    const float4 v = *reinterpret_cast<const float4*>(cb + (size_t)row * D_ + (lane << 2));
    float s = v.x * v.x + v.y * v.y + v.z * v.z + v.w * v.w;
    #pragma unroll
    for (int off = 1; off < 64; off <<= 1) s += __shfl_xor(s, off, 64);
    if (lane == 0) ww[row] = s;
}

// ---------------------------------------------------------------------------
// Prep 2: codebooks f32 -> f16 in LDS-image order.
// Granule e: lane=e&63, sub=(e>>6)&31, ch=(e>>11)&15, l=e>>15;
// n=sub&3, kk=sub>>2, g=lane>>4, c4=lane&15.
// content = cb[l][ch*64 + n*16 + c4][kk*32 + g*8 .. +8]
// ---------------------------------------------------------------------------
__global__ __launch_bounds__(256)
void rvq_cvtp_kernel(const float* __restrict__ cb, _Float16* __restrict__ cbp) {
    const int e    = blockIdx.x * 256 + threadIdx.x;
    const int lane = e & 63, sub = (e >> 6) & 31, ch = (e >> 11) & 15, l = e >> 15;
    const int n = sub & 3, kk = sub >> 2, g = lane >> 4, c4 = lane & 15;
    const float* src = cb + (size_t)(l * 1024 + ch * 64 + n * 16 + c4) * D_ + kk * 32 + g * 8;
    const float4 a = *reinterpret_cast<const float4*>(src);
    const float4 b = *reinterpret_cast<const float4*>(src + 4);
    f16x8 v;
    v[0] = (_Float16)a.x; v[1] = (_Float16)a.y; v[2] = (_Float16)a.z; v[3] = (_Float16)a.w;
    v[4] = (_Float16)b.x; v[5] = (_Float16)b.y; v[6] = (_Float16)b.z; v[7] = (_Float16)b.w;
    *reinterpret_cast<f16x8*>(cbp + (size_t)e * 8) = v;
}

// ---------------------------------------------------------------------------
// Main (R10): per-lane running argmin (no per-chunk shuffles); chunk=64
// double-buffered async LDS B; exact passes via R5-style lane-redundant
// chains reading an rf LDS mirror that aliases the staging buffer.
// ---------------------------------------------------------------------------
__global__ __launch_bounds__(256, 2)
void rvq_main_kernel(const float* __restrict__ x, const float* __restrict__ cbf,
                     const _Float16* __restrict__ cb16p, const float* __restrict__ ww,
                     float* __restrict__ out) {
    __shared__ __align__(16) float rf[64 * 260];   // 66.5 KB; bytes 0..65536 alias B-staging
    __shared__ unsigned elist[4][16][ECT];
    __shared__ int ecnt[4][16];
    char* ldsbase = (char*)rf;

    const int tid  = threadIdx.x;
    const int lane = tid & 63;
    const int wv   = tid >> 6;
    const int c4   = lane & 15;
    const int g    = lane >> 4;
    const int trow = wv * 16 + c4;
    const int tg   = blockIdx.x * 64 + trow;
    const int b    = tg >> 11;
    const int tl   = tg & (T_ - 1);
    const size_t xbase = ((size_t)b << 19) + tl;

    // residual f32 in regs: r_[kk*8+e] = r[token c4][d = kk*32 + g*8 + e]
    float r_[64];
    #pragma unroll
    for (int kk = 0; kk < 8; ++kk)
        #pragma unroll
        for (int e = 0; e < 8; ++e)
            r_[kk * 8 + e] = x[xbase + (size_t)(kk * 32 + g * 8 + e) * T_];

    // stage tile (l,ch) -> buffer (ch&1). dst is wave-uniform; HW adds lane*16.
    auto stage_tile = [&](int l, int ch) {
        const _Float16* s = cb16p + ((size_t)(l * 16 + ch) * 2048 + wv * 512 + lane) * 8;
        char* d = ldsbase + (ch & 1) * 32768 + wv * 8192;
        #pragma unroll
        for (int i = 0; i < 8; ++i)
            gls16(s + i * 512, d + i * 1024);
    };

    // prologue: stage layer-0 chunk-0
    stage_tile(0, 0);

    #pragma unroll 1
    for (int l = 0; l < L_; ++l) {
        const float* __restrict__ cblf = cbf + (size_t)l * K_ * D_;
        const float* __restrict__ wwl  = ww + l * K_;

        if (lane < 16) ecnt[wv][lane] = 0;

        // ---- rr (frozen bitwise tree) ----
        float rrv;
        {
            float Tk[8];
            #pragma unroll
            for (int kk = 0; kk < 8; ++kk) {
                float4 v;
                v.x = r_[kk * 8 + 0]; v.y = r_[kk * 8 + 1];
                v.z = r_[kk * 8 + 2]; v.w = r_[kk * 8 + 3];
                float s = v.x * v.x + v.y * v.y + v.z * v.z + v.w * v.w;
                float4 u;
                u.x = r_[kk * 8 + 4]; u.y = r_[kk * 8 + 5];
                u.z = r_[kk * 8 + 6]; u.w = r_[kk * 8 + 7];
                float s2 = u.x * u.x + u.y * u.y + u.z * u.z + u.w * u.w;
                const float p  = s + s2;
                const float po = __shfl_xor(p, 16, 64);
                const float q  = p + po;
                const float qo = __shfl_xor(q, 32, 64);
                Tk[kk] = q + qo;
            }
            const float u01 = Tk[0] + Tk[1], u23 = Tk[2] + Tk[3];
            const float u45 = Tk[4] + Tk[5], u67 = Tk[6] + Tk[7];
            rrv = (u01 + u23) + (u45 + u67);
        }

        // f16 A-fragments (frozen values)
        f16x8 fr[8];
        #pragma unroll
        for (int kk = 0; kk < 8; ++kk)
            #pragma unroll
            for (int e = 0; e < 8; ++e)
                fr[kk][e] = (_Float16)r_[kk * 8 + e];

        // per-lane running best per j
        unsigned long long bkl[4];
        #pragma unroll
        for (int j = 0; j < 4; ++j) bkl[j] = packkey(__builtin_inff(), 0u);

        asm volatile("s_waitcnt vmcnt(0)" ::: "memory");
        __syncthreads();   // tile 0 ready

        // ---- screen: 16 chunks x 64 cands, zero cross-lane ops ----
        #pragma unroll 1
        for (int ch = 0; ch < 16; ++ch) {
            if (ch < 15) stage_tile(l, ch + 1);

            const _Float16* bufp =
                (const _Float16*)(ldsbase + (ch & 1) * 32768);
            const int base = ch * 64;

            #pragma unroll
            for (int h = 0; h < 2; ++h) {
                f32x4 a0v = (f32x4){0.f, 0.f, 0.f, 0.f};
                f32x4 a1v = (f32x4){0.f, 0.f, 0.f, 0.f};
                #pragma unroll
                for (int kk = 0; kk < 8; ++kk) {
                    const f16x8 b0 = *reinterpret_cast<const f16x8*>(
                        bufp + (((kk * 4 + h * 2 + 0) * 64 + lane) * 8));
                    const f16x8 b1 = *reinterpret_cast<const f16x8*>(
                        bufp + (((kk * 4 + h * 2 + 1) * 64 + lane) * 8));
                    a0v = __builtin_amdgcn_mfma_f32_16x16x32_f16(fr[kk], b0, a0v, 0, 0, 0);
                    a1v = __builtin_amdgcn_mfma_f32_16x16x32_f16(fr[kk], b1, a1v, 0, 0, 0);
                }
                #pragma unroll
                for (int n2 = 0; n2 < 2; ++n2) {
                    const f32x4 av = n2 ? a1v : a0v;
                    const unsigned cand = (unsigned)(base + (h * 2 + n2) * 16 + c4);
                    const float wwv = wwl[cand];
                    #pragma unroll
                    for (int j = 0; j < 4; ++j) {
                        const float sc = fmaf(-2.0f, av[j], wwv);   // frozen screen score
                        const unsigned long long key = packkey(sc, cand);
                        const int tj = g * 4 + j;
                        if (key < bkl[j]) {
                            const float old = unpackf(bkl[j]);
                            if (old <= sc + THETA) {
                                const int p = atomicAdd(&ecnt[wv][tj], 1);
                                if (p < ECT)
                                    elist[wv][tj][p] =
                                        (((unsigned)(bkl[j] & 0xffffull)) << 16) | f2h_bits(old);
                            }
                            bkl[j] = key;
                        } else if (sc <= unpackf(bkl[j]) + THETA) {
                            const int p = atomicAdd(&ecnt[wv][tj], 1);
                            if (p < ECT)
                                elist[wv][tj][p] = (cand << 16) | f2h_bits(sc);
                        }
                    }
                }
            }

            asm volatile("s_waitcnt vmcnt(0)" ::: "memory");
            __syncthreads();
        }

        // ---- single final cross-lane reduce + final-best pushes ----
        unsigned long long gk[4];
        #pragma unroll
        for (int j = 0; j < 4; ++j) {
            unsigned long long k0 = bkl[j];
            #pragma unroll
            for (int off = 1; off < 16; off <<= 1) {
                const unsigned long long k2 = __shfl_xor(k0, off, 64);
                if (k2 < k0) k0 = k2;
            }
            gk[j] = k0;
            if (bkl[j] != k0) {
                const float ls = unpackf(bkl[j]);
                if (ls <= unpackf(k0) + THETA) {
                    const int tj = g * 4 + j;
                    const int p = atomicAdd(&ecnt[wv][tj], 1);
                    if (p < ECT)
                        elist[wv][tj][p] =
                            (((unsigned)(bkl[j] & 0xffffull)) << 16) | f2h_bits(ls);
                }
            }
        }

        // broadcast winner cand + gmin score to owner lanes (frozen mux)
        unsigned bc0 = (unsigned)(gk[0] & 0xffffffffull);
        unsigned bc1 = (unsigned)(gk[1] & 0xffffffffull);
        unsigned bc2 = (unsigned)(gk[2] & 0xffffffffull);
        unsigned bc3 = (unsigned)(gk[3] & 0xffffffffull);
        float gm0 = unpackf(gk[0]), gm1 = unpackf(gk[1]);
        float gm2 = unpackf(gk[2]), gm3 = unpackf(gk[3]);
        const int srcl = (c4 >> 2) << 4;
        const unsigned w0 = __shfl(bc0, srcl, 64);
        const unsigned w1 = __shfl(bc1, srcl, 64);
        const unsigned w2 = __shfl(bc2, srcl, 64);
        const unsigned w3 = __shfl(bc3, srcl, 64);
        const float s0 = __shfl(gm0, srcl, 64);
        const float s1 = __shfl(gm1, srcl, 64);
        const float s2 = __shfl(gm2, srcl, 64);
        const float s3 = __shfl(gm3, srcl, 64);
        const unsigned wa = (c4 & 1) ? w1 : w0;
        const unsigned wb = (c4 & 1) ? w3 : w2;
        const unsigned wincand = (c4 & 2) ? wb : wa;
        const float sa = (c4 & 1) ? s1 : s0;
        const float sb = (c4 & 1) ? s3 : s2;
        const float gminmy = (c4 & 2) ? sb : sa;

        // ---- write register residual to rf mirror (staging idle now) ----
        {
            float* rp = rf + trow * 260;
            #pragma unroll
            for (int kk = 0; kk < 8; ++kk) {
                float4 v0; v0.x = r_[kk*8+0]; v0.y = r_[kk*8+1]; v0.z = r_[kk*8+2]; v0.w = r_[kk*8+3];
                float4 v1; v1.x = r_[kk*8+4]; v1.y = r_[kk*8+5]; v1.z = r_[kk*8+6]; v1.w = r_[kk*8+7];
                *reinterpret_cast<float4*>(rp + kk * 32 + g * 8)     = v0;
                *reinterpret_cast<float4*>(rp + kk * 32 + g * 8 + 4) = v1;
            }
        }
        asm volatile("s_waitcnt lgkmcnt(0)" ::: "memory");   // wave-internal rf visible

        // ---- exact winner: R5-style lane-redundant sequential 256-fmaf chain ----
        unsigned long long bestk;
        {
            const float* rp = rf + trow * 260;
            const float* wp = cblf + (size_t)wincand * D_;
            float a0 = 0.0f;
            #pragma unroll 4
            for (int dc = 0; dc < D_; dc += 8) {
                const float4 ra = *reinterpret_cast<const float4*>(rp + dc);
                const float4 rb = *reinterpret_cast<const float4*>(rp + dc + 4);
                const float4 wa4 = *reinterpret_cast<const float4*>(wp + dc);
                const float4 wb4 = *reinterpret_cast<const float4*>(wp + dc + 4);
                a0 = fmaf(wa4.x, ra.x, a0);
                a0 = fmaf(wa4.y, ra.y, a0);
                a0 = fmaf(wa4.z, ra.z, a0);
                a0 = fmaf(wa4.w, ra.w, a0);
                a0 = fmaf(wb4.x, rb.x, a0);
                a0 = fmaf(wb4.y, rb.y, a0);
                a0 = fmaf(wb4.z, rb.z, a0);
                a0 = fmaf(wb4.w, rb.w, a0);
            }
            const float scw = __fadd_rn(__fsub_rn(rrv, __fmul_rn(2.0f, a0)), wwl[wincand]);
            bestk = packkey(scw, wincand);
        }

        // ---- extras: filter vs gmin+theta, rare exact chains ----
        {
            const int myn = min(ecnt[wv][c4], ECT);
            const float gth = gminmy + THETA + 0.5f;   // f16-rounding margin
            const float* rp = rf + trow * 260;
            #pragma unroll 1
            for (int i = 0; i < myn; ++i) {
                const unsigned e  = elist[wv][c4][i];
                const unsigned ec = e >> 16;
                const float hsc = h_bits2f((unsigned short)(e & 0xffffu));
                if (ec == wincand || hsc > gth) continue;
                const float* ep = cblf + (size_t)ec * D_;
                float q = 0.0f;
                #pragma unroll 4
                for (int dc = 0; dc < D_; dc += 8) {
                    const float4 ra = *reinterpret_cast<const float4*>(rp + dc);
                    const float4 rb = *reinterpret_cast<const float4*>(rp + dc + 4);
                    const float4 wa4 = *reinterpret_cast<const float4*>(ep + dc);
                    const float4 wb4 = *reinterpret_cast<const float4*>(ep + dc + 4);
                    q = fmaf(wa4.x, ra.x, q);
                    q = fmaf(wa4.y, ra.y, q);
                    q = fmaf(wa4.z, ra.z, q);
                    q = fmaf(wa4.w, ra.w, q);
                    q = fmaf(wb4.x, rb.x, q);
                    q = fmaf(wb4.y, rb.y, q);
                    q = fmaf(wb4.z, rb.z, q);
                    q = fmaf(wb4.w, rb.w, q);
                }
                const float sce = __fadd_rn(__fsub_rn(rrv, __fmul_rn(2.0f, q)), wwl[ec]);
                const unsigned long long k2 = packkey(sce, ec);
                if (k2 < bestk) bestk = k2;
            }
        }

        const unsigned fc = (unsigned)(bestk & 0xffffffffull);
        if (g == 0)
            out[(size_t)B_ * D_ * T_ + ((size_t)b * L_ + l) * T_ + tl] = (float)fc;

        // ---- residual update (frozen element-wise f32) ----
        {
            const float* up = cblf + (size_t)fc * D_;
            #pragma unroll
            for (int kk = 0; kk < 8; ++kk) {
                const float4 ua = *reinterpret_cast<const float4*>(up + kk * 32 + g * 8);
                const float4 ub = *reinterpret_cast<const float4*>(up + kk * 32 + g * 8 + 4);
                r_[kk * 8 + 0] = __fsub_rn(r_[kk * 8 + 0], ua.x);
                r_[kk * 8 + 1] = __fsub_rn(r_[kk * 8 + 1], ua.y);
                r_[kk * 8 + 2] = __fsub_rn(r_[kk * 8 + 2], ua.z);
                r_[kk * 8 + 3] = __fsub_rn(r_[kk * 8 + 3], ua.w);
                r_[kk * 8 + 4] = __fsub_rn(r_[kk * 8 + 4], ub.x);
                r_[kk * 8 + 5] = __fsub_rn(r_[kk * 8 + 5], ub.y);
                r_[kk * 8 + 6] = __fsub_rn(r_[kk * 8 + 6], ub.z);
                r_[kk * 8 + 7] = __fsub_rn(r_[kk * 8 + 7], ub.w);
            }
        }

        __syncthreads();   // all waves done with rf; staging may overwrite
        if (l < L_ - 1) stage_tile(l + 1, 0);
    }

    // epilogue (frozen): quantized = x - r_final
    #pragma unroll
    for (int kk = 0; kk < 8; ++kk)
        #pragma unroll
        for (int e = 0; e < 8; ++e) {
            const size_t gi = xbase + (size_t)(kk * 32 + g * 8 + e) * T_;
            out[gi] = __fsub_rn(x[gi], r_[kk * 8 + e]);
        }
}

extern "C" void kernel_launch(void* const* d_in, const int* in_sizes, int n_in,
                              void* d_out, int out_size, void* d_ws, size_t ws_size,
                              hipStream_t stream) {
    const float* x  = (const float*)d_in[0];
    const float* cb = (const float*)d_in[1];
    float* out = (float*)d_out;
    float*    ww    = (float*)d_ws;                       // 32 KB
    _Float16* cb16p = (_Float16*)((char*)d_ws + 32768);   // 4 MB (permuted)

    hipLaunchKernelGGL(rvq_ww_kernel,   dim3((L_ * K_) / 4), dim3(256), 0, stream, cb, ww);
    hipLaunchKernelGGL(rvq_cvtp_kernel, dim3(1024), dim3(256), 0, stream, cb, cb16p);
    hipLaunchKernelGGL(rvq_main_kernel, dim3((B_ * T_) / 64), dim3(256), 0, stream,
                       x, cb, cb16p, ww, out);
}

// Round 11
// 530.933 us; speedup vs baseline: 2.4377x; 1.0520x over previous
//
#include <hip/hip_runtime.h>

#define D_ 256
#define T_ 2048
#define K_ 1024
#define L_ 8
#define B_ 16
#define THETA 0.5f
#define ECT 40
#define NTILE 256   // L_ * 32 tiles of 32 candidates

typedef _Float16 f16x8 __attribute__((ext_vector_type(8)));
typedef float    f32x4 __attribute__((ext_vector_type(4)));

typedef const __attribute__((address_space(1))) unsigned int* gas1_t;
typedef __attribute__((address_space(3))) unsigned int*       las3_t;

__device__ __forceinline__ void gls16(const void* g, void* l) {
    __builtin_amdgcn_global_load_lds((gas1_t)g, (las3_t)l, 16, 0, 0);
}
__device__ __forceinline__ void gls4(const void* g, void* l) {
    __builtin_amdgcn_global_load_lds((gas1_t)g, (las3_t)l, 4, 0, 0);
}

__device__ __forceinline__ unsigned long long packkey(float sc, unsigned cand) {
    const unsigned fb = __float_as_uint(sc);
    const unsigned ob = fb ^ ((unsigned)((int)fb >> 31) | 0x80000000u);
    return (((unsigned long long)ob) << 32) | cand;
}
__device__ __forceinline__ float unpackf(unsigned long long key) {
    const unsigned ob = (unsigned)(key >> 32);
    const unsigned fb = (ob & 0x80000000u) ? (ob ^ 0x80000000u) : ~ob;
    return __uint_as_float(fb);
}
__device__ __forceinline__ unsigned short f2h_bits(float s) {
    union { _Float16 f; unsigned short u; } cv; cv.f = (_Float16)s; return cv.u;
}
__device__ __forceinline__ float h_bits2f(unsigned short u) {
    union { _Float16 f; unsigned short u; } cv; cv.u = u; return (float)cv.f;
}

// ---------------------------------------------------------------------------
// Prep 1 (frozen): ww[l*K + c] = ||codebook[l][c]||^2
// ---------------------------------------------------------------------------
__global__ __launch_bounds__(256, 4)
void rvq_ww_kernel(const float* __restrict__ cb, float* __restrict__ ww) {
    const int row  = blockIdx.x * 4 + (threadIdx.x >> 6);
    const int lane = threadIdx.x & 63;
    const float4 v = *reinterpret_cast<const float4*>(cb + (size_t)row * D_ + (lane << 2));
    float s = v.x * v.x + v.y * v.y + v.z * v.z + v.w * v.w;
    #pragma unroll
    for (int off = 1; off < 64; off <<= 1) s += __shfl_xor(s, off, 64);
    if (lane == 0) ww[row] = s;
}

// ---------------------------------------------------------------------------
// Prep 2 (frozen, R9): codebooks f32 -> f16 in LDS-image order.
// Granule e: lane=e&63, sub=(e>>6)&15, ch=(e>>10)&31, l=e>>15;
// n=sub&1, kk=sub>>1; content = cb[l][ch*32+n*16+c4][kk*32+g*8 ..]
// ---------------------------------------------------------------------------
__global__ __launch_bounds__(256)
void rvq_cvtp_kernel(const float* __restrict__ cb, _Float16* __restrict__ cbp) {
    const int e    = blockIdx.x * 256 + threadIdx.x;
    const int lane = e & 63, sub = (e >> 6) & 15, ch = (e >> 10) & 31, l = e >> 15;
    const int n = sub & 1, kk = sub >> 1, g = lane >> 4, c4 = lane & 15;
    const float* src = cb + (size_t)(l * 1024 + ch * 32 + n * 16 + c4) * D_ + kk * 32 + g * 8;
    const float4 a = *reinterpret_cast<const float4*>(src);
    const float4 b = *reinterpret_cast<const float4*>(src + 4);
    f16x8 v;
    v[0] = (_Float16)a.x; v[1] = (_Float16)a.y; v[2] = (_Float16)a.z; v[3] = (_Float16)a.w;
    v[4] = (_Float16)b.x; v[5] = (_Float16)b.y; v[6] = (_Float16)b.z; v[7] = (_Float16)b.w;
    *reinterpret_cast<f16x8*>(cbp + (size_t)e * 8) = v;
}

// ---------------------------------------------------------------------------
// Main (R11): 3-tile rotating async-DMA pipeline with counted vmcnt(6) and
// raw s_barrier (T3/T4); per-lane running argmin (R10); exact passes via
// R8-validated 4-lane relay. All decision arithmetic frozen.
// ---------------------------------------------------------------------------
__global__ __launch_bounds__(256, 2)
void rvq_main_kernel(const float* __restrict__ x, const float* __restrict__ cbf,
                     const _Float16* __restrict__ cb16p, const float* __restrict__ ww,
                     float* __restrict__ out) {
    __shared__ __align__(16) _Float16 bstage[3][8192];   // 3 x 16 KB tiles
    __shared__ float    wwlds[3][64];
    __shared__ unsigned elist[4][16][ECT];
    __shared__ int      ecnt[4][16];

    const int tid  = threadIdx.x;
    const int lane = tid & 63;
    const int wv   = tid >> 6;
    const int c4   = lane & 15;
    const int g    = lane >> 4;
    const int tg   = blockIdx.x * 64 + wv * 16 + c4;
    const int b    = tg >> 11;
    const int tl   = tg & (T_ - 1);
    const size_t xbase = ((size_t)b << 19) + tl;

    // stage global tile gt -> buffer gt%3 (6 DMA ops per wave per tile)
    auto stage_tile = [&](int gt) {
        const int bufi = gt % 3;
        const _Float16* s = cb16p + ((size_t)gt * 1024 + wv * 256 + lane) * 8;
        char* d = (char*)bstage[bufi] + wv * 4096;
        #pragma unroll
        for (int i = 0; i < 4; ++i)
            gls16(s + i * 512, d + i * 1024);
        gls4(ww + gt * 32 + lane, &wwlds[bufi][0]);
    };

    stage_tile(0);
    stage_tile(1);

    // residual f32 in regs: r_[kk*8+e] = r[token c4][d = kk*32 + g*8 + e]
    float r_[64];
    #pragma unroll
    for (int kk = 0; kk < 8; ++kk)
        #pragma unroll
        for (int e = 0; e < 8; ++e)
            r_[kk * 8 + e] = x[xbase + (size_t)(kk * 32 + g * 8 + e) * T_];

    #pragma unroll 1
    for (int l = 0; l < L_; ++l) {
        const float* __restrict__ cblf = cbf + (size_t)l * K_ * D_;
        const float* __restrict__ wwl  = ww + l * K_;

        if (lane < 16) ecnt[wv][lane] = 0;

        // ---- rr (frozen bitwise tree) ----
        float rrv;
        {
            float Tk[8];
            #pragma unroll
            for (int kk = 0; kk < 8; ++kk) {
                float4 v;
                v.x = r_[kk * 8 + 0]; v.y = r_[kk * 8 + 1];
                v.z = r_[kk * 8 + 2]; v.w = r_[kk * 8 + 3];
                float s = v.x * v.x + v.y * v.y + v.z * v.z + v.w * v.w;
                float4 u;
                u.x = r_[kk * 8 + 4]; u.y = r_[kk * 8 + 5];
                u.z = r_[kk * 8 + 6]; u.w = r_[kk * 8 + 7];
                float s2 = u.x * u.x + u.y * u.y + u.z * u.z + u.w * u.w;
                const float p  = s + s2;
                const float po = __shfl_xor(p, 16, 64);
                const float q  = p + po;
                const float qo = __shfl_xor(q, 32, 64);
                Tk[kk] = q + qo;
            }
            const float u01 = Tk[0] + Tk[1], u23 = Tk[2] + Tk[3];
            const float u45 = Tk[4] + Tk[5], u67 = Tk[6] + Tk[7];
            rrv = (u01 + u23) + (u45 + u67);
        }

        // f16 A-fragments (frozen values)
        f16x8 fr[8];
        #pragma unroll
        for (int kk = 0; kk < 8; ++kk)
            #pragma unroll
            for (int e = 0; e < 8; ++e)
                fr[kk][e] = (_Float16)r_[kk * 8 + e];

        unsigned long long bkl[4];
        float bth[4];
        #pragma unroll
        for (int j = 0; j < 4; ++j) {
            bkl[j] = packkey(__builtin_inff(), 0u);
            bth[j] = __builtin_inff();
        }

        asm volatile("s_waitcnt vmcnt(0)" ::: "memory");
        __builtin_amdgcn_s_barrier();

        // ---- screen: 32 chunks x 32 cands; 3-tile counted-vmcnt pipeline ----
        #pragma unroll 1
        for (int c = 0; c < 32; ++c) {
            const int gt   = l * 32 + c;
            const int bufi = gt % 3;
            const bool pf  = (gt + 2 < NTILE);
            if (pf) stage_tile(gt + 2);

            const _Float16* bufp = bstage[bufi];
            const int base = c * 32;
            f32x4 acc0 = (f32x4){0.f, 0.f, 0.f, 0.f};
            f32x4 acc1 = (f32x4){0.f, 0.f, 0.f, 0.f};

            #pragma unroll
            for (int kk = 0; kk < 8; ++kk) {
                const f16x8 b0 = *reinterpret_cast<const f16x8*>(
                    bufp + ((kk * 2 + 0) * 64 + lane) * 8);
                const f16x8 b1 = *reinterpret_cast<const f16x8*>(
                    bufp + ((kk * 2 + 1) * 64 + lane) * 8);
                acc0 = __builtin_amdgcn_mfma_f32_16x16x32_f16(fr[kk], b0, acc0, 0, 0, 0);
                acc1 = __builtin_amdgcn_mfma_f32_16x16x32_f16(fr[kk], b1, acc1, 0, 0, 0);
            }

            const float ww0 = wwlds[bufi][c4];
            const float ww1 = wwlds[bufi][16 + c4];

            #pragma unroll
            for (int n2 = 0; n2 < 2; ++n2) {
                const f32x4 av = n2 ? acc1 : acc0;
                const unsigned cand = (unsigned)(base + n2 * 16 + c4);
                const float wwv = n2 ? ww1 : ww0;
                #pragma unroll
                for (int j = 0; j < 4; ++j) {
                    const float sc = fmaf(-2.0f, av[j], wwv);   // frozen screen score
                    const unsigned long long key = packkey(sc, cand);
                    const int tj = g * 4 + j;
                    if (key < bkl[j]) {
                        const float old = unpackf(bkl[j]);
                        if (old <= sc + THETA) {
                            const int p = atomicAdd(&ecnt[wv][tj], 1);
                            if (p < ECT)
                                elist[wv][tj][p] =
                                    (((unsigned)(bkl[j] & 0xffffull)) << 16) | f2h_bits(old);
                        }
                        bkl[j] = key;
                        bth[j] = sc + THETA;
                    } else if (sc <= bth[j]) {
                        const int p = atomicAdd(&ecnt[wv][tj], 1);
                        if (p < ECT)
                            elist[wv][tj][p] = (cand << 16) | f2h_bits(sc);
                    }
                }
            }

            if (pf) { asm volatile("s_waitcnt vmcnt(6)" ::: "memory"); }
            else    { asm volatile("s_waitcnt vmcnt(0)" ::: "memory"); }
            __builtin_amdgcn_s_barrier();
        }

        // ---- final cross-lane reduce + final-best pushes (R10 frozen) ----
        unsigned long long gk[4];
        #pragma unroll
        for (int j = 0; j < 4; ++j) {
            unsigned long long k0 = bkl[j];
            #pragma unroll
            for (int off = 1; off < 16; off <<= 1) {
                const unsigned long long k2 = __shfl_xor(k0, off, 64);
                if (k2 < k0) k0 = k2;
            }
            gk[j] = k0;
            if (bkl[j] != k0) {
                const float ls = unpackf(bkl[j]);
                if (ls <= unpackf(k0) + THETA) {
                    const int tj = g * 4 + j;
                    const int p = atomicAdd(&ecnt[wv][tj], 1);
                    if (p < ECT)
                        elist[wv][tj][p] =
                            (((unsigned)(bkl[j] & 0xffffull)) << 16) | f2h_bits(ls);
                }
            }
        }

        // broadcast winner + gmin to owner lanes (frozen mux)
        unsigned bc0 = (unsigned)(gk[0] & 0xffffffffull);
        unsigned bc1 = (unsigned)(gk[1] & 0xffffffffull);
        unsigned bc2 = (unsigned)(gk[2] & 0xffffffffull);
        unsigned bc3 = (unsigned)(gk[3] & 0xffffffffull);
        float gm0 = unpackf(gk[0]), gm1 = unpackf(gk[1]);
        float gm2 = unpackf(gk[2]), gm3 = unpackf(gk[3]);
        const int srcl = (c4 >> 2) << 4;
        const unsigned w0 = __shfl(bc0, srcl, 64);
        const unsigned w1 = __shfl(bc1, srcl, 64);
        const unsigned w2 = __shfl(bc2, srcl, 64);
        const unsigned w3 = __shfl(bc3, srcl, 64);
        const float s0 = __shfl(gm0, srcl, 64);
        const float s1 = __shfl(gm1, srcl, 64);
        const float s2 = __shfl(gm2, srcl, 64);
        const float s3 = __shfl(gm3, srcl, 64);
        const unsigned wa = (c4 & 1) ? w1 : w0;
        const unsigned wb = (c4 & 1) ? w3 : w2;
        const unsigned wincand = (c4 & 2) ? wb : wa;
        const float sa = (c4 & 1) ? s1 : s0;
        const float sb = (c4 & 1) ? s3 : s2;
        const float gminmy = (c4 & 2) ? sb : sa;

        // ---- exact winner: R8-validated 4-lane relay (frozen) ----
        unsigned long long bestk;
        {
            const float* wp = cblf + (size_t)wincand * D_;
            float4 wA = *reinterpret_cast<const float4*>(wp + g * 8);
            float4 wB = *reinterpret_cast<const float4*>(wp + g * 8 + 4);
            float4 nA = *reinterpret_cast<const float4*>(wp + 32 + g * 8);
            float4 nB = *reinterpret_cast<const float4*>(wp + 32 + g * 8 + 4);
            float a0 = 0.0f;
            #pragma unroll
            for (int s = 0; s < 32; ++s) {
                const int kk = s >> 2;
                if ((s & 3) == g) {
                    a0 = fmaf(wA.x, r_[kk * 8 + 0], a0);
                    a0 = fmaf(wA.y, r_[kk * 8 + 1], a0);
                    a0 = fmaf(wA.z, r_[kk * 8 + 2], a0);
                    a0 = fmaf(wA.w, r_[kk * 8 + 3], a0);
                    a0 = fmaf(wB.x, r_[kk * 8 + 4], a0);
                    a0 = fmaf(wB.y, r_[kk * 8 + 5], a0);
                    a0 = fmaf(wB.z, r_[kk * 8 + 6], a0);
                    a0 = fmaf(wB.w, r_[kk * 8 + 7], a0);
                    wA = nA; wB = nB;
                    if (kk + 2 < 8) {
                        nA = *reinterpret_cast<const float4*>(wp + (kk + 2) * 32 + g * 8);
                        nB = *reinterpret_cast<const float4*>(wp + (kk + 2) * 32 + g * 8 + 4);
                    }
                }
                a0 = __shfl(a0, (lane + 48) & 63, 64);
            }
            a0 = __shfl(a0, c4, 64);
            const float scw = __fadd_rn(__fsub_rn(rrv, __fmul_rn(2.0f, a0)), wwl[wincand]);
            bestk = packkey(scw, wincand);
        }

        // ---- extras: per-token relay with gmin filter (frozen pieces) ----
        {
            const int myn = min(ecnt[wv][c4], ECT);
            const float gth = gminmy + THETA + 0.5f;   // f16-rounding margin
            #pragma unroll 1
            for (int i = 0; i < myn; ++i) {
                const unsigned e  = elist[wv][c4][i];
                const unsigned ec = e >> 16;
                const float hsc = h_bits2f((unsigned short)(e & 0xffffu));
                if (ec == wincand || hsc > gth) continue;
                const float* ep = cblf + (size_t)ec * D_;
                float4 wA = *reinterpret_cast<const float4*>(ep + g * 8);
                float4 wB = *reinterpret_cast<const float4*>(ep + g * 8 + 4);
                float4 nA = *reinterpret_cast<const float4*>(ep + 32 + g * 8);
                float4 nB = *reinterpret_cast<const float4*>(ep + 32 + g * 8 + 4);
                float q = 0.0f;
                #pragma unroll
                for (int s = 0; s < 32; ++s) {
                    const int kk = s >> 2;
                    if ((s & 3) == g) {
                        q = fmaf(wA.x, r_[kk * 8 + 0], q);
                        q = fmaf(wA.y, r_[kk * 8 + 1], q);
                        q = fmaf(wA.z, r_[kk * 8 + 2], q);
                        q = fmaf(wA.w, r_[kk * 8 + 3], q);
                        q = fmaf(wB.x, r_[kk * 8 + 4], q);
                        q = fmaf(wB.y, r_[kk * 8 + 5], q);
                        q = fmaf(wB.z, r_[kk * 8 + 6], q);
                        q = fmaf(wB.w, r_[kk * 8 + 7], q);
                        wA = nA; wB = nB;
                        if (kk + 2 < 8) {
                            nA = *reinterpret_cast<const float4*>(ep + (kk + 2) * 32 + g * 8);
                            nB = *reinterpret_cast<const float4*>(ep + (kk + 2) * 32 + g * 8 + 4);
                        }
                    }
                    q = __shfl(q, (lane + 48) & 63, 64);
                }
                q = __shfl(q, c4, 64);
                const float sce = __fadd_rn(__fsub_rn(rrv, __fmul_rn(2.0f, q)), wwl[ec]);
                const unsigned long long k2 = packkey(sce, ec);
                if (k2 < bestk) bestk = k2;
            }
        }

        const unsigned fc = (unsigned)(bestk & 0xffffffffull);
        if (g == 0)
            out[(size_t)B_ * D_ * T_ + ((size_t)b * L_ + l) * T_ + tl] = (float)fc;

        // ---- residual update (frozen element-wise f32) ----
        {
            const float* up = cblf + (size_t)fc * D_;
            #pragma unroll
            for (int kk = 0; kk < 8; ++kk) {
                const float4 ua = *reinterpret_cast<const float4*>(up + kk * 32 + g * 8);
                const float4 ub = *reinterpret_cast<const float4*>(up + kk * 32 + g * 8 + 4);
                r_[kk * 8 + 0] = __fsub_rn(r_[kk * 8 + 0], ua.x);
                r_[kk * 8 + 1] = __fsub_rn(r_[kk * 8 + 1], ua.y);
                r_[kk * 8 + 2] = __fsub_rn(r_[kk * 8 + 2], ua.z);
                r_[kk * 8 + 3] = __fsub_rn(r_[kk * 8 + 3], ua.w);
                r_[kk * 8 + 4] = __fsub_rn(r_[kk * 8 + 4], ub.x);
                r_[kk * 8 + 5] = __fsub_rn(r_[kk * 8 + 5], ub.y);
                r_[kk * 8 + 6] = __fsub_rn(r_[kk * 8 + 6], ub.z);
                r_[kk * 8 + 7] = __fsub_rn(r_[kk * 8 + 7], ub.w);
            }
        }
    }

    // epilogue (frozen): quantized = x - r_final
    #pragma unroll
    for (int kk = 0; kk < 8; ++kk)
        #pragma unroll
        for (int e = 0; e < 8; ++e) {
            const size_t gi = xbase + (size_t)(kk * 32 + g * 8 + e) * T_;
            out[gi] = __fsub_rn(x[gi], r_[kk * 8 + e]);
        }
}

extern "C" void kernel_launch(void* const* d_in, const int* in_sizes, int n_in,
                              void* d_out, int out_size, void* d_ws, size_t ws_size,
                              hipStream_t stream) {
    const float* x  = (const float*)d_in[0];
    const float* cb = (const float*)d_in[1];
    float* out = (float*)d_out;
    float*    ww    = (float*)d_ws;                       // 32 KB
    _Float16* cb16p = (_Float16*)((char*)d_ws + 32768);   // 4 MB (permuted)

    hipLaunchKernelGGL(rvq_ww_kernel,   dim3((L_ * K_) / 4), dim3(256), 0, stream, cb, ww);
    hipLaunchKernelGGL(rvq_cvtp_kernel, dim3(1024), dim3(256), 0, stream, cb, cb16p);
    hipLaunchKernelGGL(rvq_main_kernel, dim3((B_ * T_) / 64), dim3(256), 0, stream,
                       x, cb, cb16p, ww, out);
}

// Round 12
// 528.913 us; speedup vs baseline: 2.4470x; 1.0038x over previous
//
#include <hip/hip_runtime.h>

#define D_ 256
#define T_ 2048
#define K_ 1024
#define L_ 8
#define B_ 16
#define THETA 0.5f
#define ECT 40
#define NTILE 64   // L_ * 8 tiles of 128 candidates

typedef _Float16 f16x8 __attribute__((ext_vector_type(8)));
typedef float    f32x4 __attribute__((ext_vector_type(4)));

typedef const __attribute__((address_space(1))) unsigned int* gas1_t;
typedef __attribute__((address_space(3))) unsigned int*       las3_t;

__device__ __forceinline__ void gls16(const void* g, void* l) {
    __builtin_amdgcn_global_load_lds((gas1_t)g, (las3_t)l, 16, 0, 0);
}
__device__ __forceinline__ void gls4(const void* g, void* l) {
    __builtin_amdgcn_global_load_lds((gas1_t)g, (las3_t)l, 4, 0, 0);
}

__device__ __forceinline__ unsigned long long packkey(float sc, unsigned cand) {
    const unsigned fb = __float_as_uint(sc);
    const unsigned ob = fb ^ ((unsigned)((int)fb >> 31) | 0x80000000u);
    return (((unsigned long long)ob) << 32) | cand;
}
__device__ __forceinline__ float unpackf(unsigned long long key) {
    const unsigned ob = (unsigned)(key >> 32);
    const unsigned fb = (ob & 0x80000000u) ? (ob ^ 0x80000000u) : ~ob;
    return __uint_as_float(fb);
}
__device__ __forceinline__ unsigned short f2h_bits(float s) {
    union { _Float16 f; unsigned short u; } cv; cv.f = (_Float16)s; return cv.u;
}
__device__ __forceinline__ float h_bits2f(unsigned short u) {
    union { _Float16 f; unsigned short u; } cv; cv.u = u; return (float)cv.f;
}

// ---------------------------------------------------------------------------
// Prep 1 (frozen): ww[l*K + c] = ||codebook[l][c]||^2
// ---------------------------------------------------------------------------
__global__ __launch_bounds__(256, 4)
void rvq_ww_kernel(const float* __restrict__ cb, float* __restrict__ ww) {
    const int row  = blockIdx.x * 4 + (threadIdx.x >> 6);
    const int lane = threadIdx.x & 63;
    const float4 v = *reinterpret_cast<const float4*>(cb + (size_t)row * D_ + (lane << 2));
    float s = v.x * v.x + v.y * v.y + v.z * v.z + v.w * v.w;
    #pragma unroll
    for (int off = 1; off < 64; off <<= 1) s += __shfl_xor(s, off, 64);
    if (lane == 0) ww[row] = s;
}

// ---------------------------------------------------------------------------
// Prep 2: codebooks f32 -> f16 in 64KB-tile LDS-image order.
// Granule e (16B): gt=e>>12 (tile = l*8+ch), q=e&4095, lane=q&63, nk=q>>6,
// n=nk&7, kk=nk>>3, c4=lane&15, g=lane>>4;
// content = cb[l][ch*128 + n*16 + c4][kk*32 + g*8 .. +8]
// ---------------------------------------------------------------------------
__global__ __launch_bounds__(256)
void rvq_cvtp_kernel(const float* __restrict__ cb, _Float16* __restrict__ cbp) {
    const int e    = blockIdx.x * 256 + threadIdx.x;
    const int gt   = e >> 12, q = e & 4095;
    const int lane = q & 63, nk = q >> 6;
    const int n = nk & 7, kk = nk >> 3, c4 = lane & 15, g = lane >> 4;
    const int l = gt >> 3, ch = gt & 7;
    const float* src = cb + (size_t)(l * 1024 + ch * 128 + n * 16 + c4) * D_ + kk * 32 + g * 8;
    const float4 a = *reinterpret_cast<const float4*>(src);
    const float4 b = *reinterpret_cast<const float4*>(src + 4);
    f16x8 v;
    v[0] = (_Float16)a.x; v[1] = (_Float16)a.y; v[2] = (_Float16)a.z; v[3] = (_Float16)a.w;
    v[4] = (_Float16)b.x; v[5] = (_Float16)b.y; v[6] = (_Float16)b.z; v[7] = (_Float16)b.w;
    *reinterpret_cast<f16x8*>(cbp + (size_t)e * 8) = v;
}

// ---------------------------------------------------------------------------
// Main (R12): 512 threads (8 waves), 1 block/CU; 2x64KB double-buffered
// async-DMA B tiles (128 cands -> 8 barriers/layer, 4x fewer); per-lane
// running argmin; exact passes via 4-lane relay. Decision arithmetic frozen.
// ---------------------------------------------------------------------------
__global__ __launch_bounds__(512, 2)
void rvq_main_kernel(const float* __restrict__ x, const float* __restrict__ cbf,
                     const _Float16* __restrict__ cb16p, const float* __restrict__ ww,
                     float* __restrict__ out) {
    __shared__ __align__(16) _Float16 bstage[2][32768];   // 2 x 64 KB tiles
    __shared__ float    wwlds[2][128];
    __shared__ unsigned elist[8][16][ECT];
    __shared__ int      ecnt[8][16];

    const int tid  = threadIdx.x;
    const int lane = tid & 63;
    const int wv   = tid >> 6;          // 0..7
    const int c4   = lane & 15;
    const int g    = lane >> 4;
    const int tg   = blockIdx.x * 128 + wv * 16 + c4;
    const int b    = tg >> 11;
    const int tl   = tg & (T_ - 1);
    const size_t xbase = ((size_t)b << 19) + tl;

    // stage global tile gt -> buffer gt&1 (8 gls16/wave; ww by waves 0,1)
    auto stage_tile = [&](int gt) {
        const _Float16* s = cb16p + ((size_t)gt * 4096 + wv * 512 + lane) * 8;
        char* d = (char*)bstage[gt & 1] + wv * 8192;
        #pragma unroll
        for (int i = 0; i < 8; ++i)
            gls16(s + i * 512, d + i * 1024);
        if (wv < 2)
            gls4(ww + gt * 128 + wv * 64 + lane, &wwlds[gt & 1][wv * 64]);
    };

    stage_tile(0);

    // residual f32 in regs: r_[kk*8+e] = r[token c4][d = kk*32 + g*8 + e]
    float r_[64];
    #pragma unroll
    for (int kk = 0; kk < 8; ++kk)
        #pragma unroll
        for (int e = 0; e < 8; ++e)
            r_[kk * 8 + e] = x[xbase + (size_t)(kk * 32 + g * 8 + e) * T_];

    __syncthreads();   // tile 0 resident (implicit vmcnt(0) drain)

    #pragma unroll 1
    for (int l = 0; l < L_; ++l) {
        const float* __restrict__ cblf = cbf + (size_t)l * K_ * D_;
        const float* __restrict__ wwl  = ww + l * K_;

        if (lane < 16) ecnt[wv][lane] = 0;

        // ---- rr (frozen bitwise tree) ----
        float rrv;
        {
            float Tk[8];
            #pragma unroll
            for (int kk = 0; kk < 8; ++kk) {
                float4 v;
                v.x = r_[kk * 8 + 0]; v.y = r_[kk * 8 + 1];
                v.z = r_[kk * 8 + 2]; v.w = r_[kk * 8 + 3];
                float s = v.x * v.x + v.y * v.y + v.z * v.z + v.w * v.w;
                float4 u;
                u.x = r_[kk * 8 + 4]; u.y = r_[kk * 8 + 5];
                u.z = r_[kk * 8 + 6]; u.w = r_[kk * 8 + 7];
                float s2 = u.x * u.x + u.y * u.y + u.z * u.z + u.w * u.w;
                const float p  = s + s2;
                const float po = __shfl_xor(p, 16, 64);
                const float q  = p + po;
                const float qo = __shfl_xor(q, 32, 64);
                Tk[kk] = q + qo;
            }
            const float u01 = Tk[0] + Tk[1], u23 = Tk[2] + Tk[3];
            const float u45 = Tk[4] + Tk[5], u67 = Tk[6] + Tk[7];
            rrv = (u01 + u23) + (u45 + u67);
        }

        // f16 A-fragments (frozen values)
        f16x8 fr[8];
        #pragma unroll
        for (int kk = 0; kk < 8; ++kk)
            #pragma unroll
            for (int e = 0; e < 8; ++e)
                fr[kk][e] = (_Float16)r_[kk * 8 + e];

        unsigned long long bkl[4];
        float bth[4];
        #pragma unroll
        for (int j = 0; j < 4; ++j) {
            bkl[j] = packkey(__builtin_inff(), 0u);
            bth[j] = __builtin_inff();
        }

        // ---- screen: 8 chunks x 128 cands; dbuf async DMA, 1 barrier/chunk ----
        #pragma unroll 1
        for (int c = 0; c < 8; ++c) {
            const int gt = l * 8 + c;
            if (gt + 1 < NTILE) stage_tile(gt + 1);

            const _Float16* bufp = bstage[gt & 1];
            const float*    wwp  = wwlds[gt & 1];
            const int base = c * 128;

            f32x4 acc[8];
            #pragma unroll
            for (int n = 0; n < 8; ++n) acc[n] = (f32x4){0.f, 0.f, 0.f, 0.f};

            #pragma unroll
            for (int kk = 0; kk < 8; ++kk) {
                #pragma unroll
                for (int n = 0; n < 8; ++n) {
                    const f16x8 bf = *reinterpret_cast<const f16x8*>(
                        bufp + ((kk * 8 + n) * 64 + lane) * 8);
                    acc[n] = __builtin_amdgcn_mfma_f32_16x16x32_f16(fr[kk], bf, acc[n], 0, 0, 0);
                }
            }

            #pragma unroll
            for (int n = 0; n < 8; ++n) {
                const unsigned cand = (unsigned)(base + n * 16 + c4);
                const float wwv = wwp[n * 16 + c4];
                #pragma unroll
                for (int j = 0; j < 4; ++j) {
                    const float sc = fmaf(-2.0f, acc[n][j], wwv);   // frozen screen score
                    const unsigned long long key = packkey(sc, cand);
                    const int tj = g * 4 + j;
                    if (key < bkl[j]) {
                        const float old = unpackf(bkl[j]);
                        if (old <= sc + THETA) {
                            const int p = atomicAdd(&ecnt[wv][tj], 1);
                            if (p < ECT)
                                elist[wv][tj][p] =
                                    (((unsigned)(bkl[j] & 0xffffull)) << 16) | f2h_bits(old);
                        }
                        bkl[j] = key;
                        bth[j] = sc + THETA;
                    } else if (sc <= bth[j]) {
                        const int p = atomicAdd(&ecnt[wv][tj], 1);
                        if (p < ECT)
                            elist[wv][tj][p] = (cand << 16) | f2h_bits(sc);
                    }
                }
            }

            __syncthreads();   // drain DMA (implicit vmcnt 0) + tile handoff
        }

        // ---- final cross-lane reduce + final-best pushes (frozen) ----
        unsigned long long gk[4];
        #pragma unroll
        for (int j = 0; j < 4; ++j) {
            unsigned long long k0 = bkl[j];
            #pragma unroll
            for (int off = 1; off < 16; off <<= 1) {
                const unsigned long long k2 = __shfl_xor(k0, off, 64);
                if (k2 < k0) k0 = k2;
            }
            gk[j] = k0;
            if (bkl[j] != k0) {
                const float ls = unpackf(bkl[j]);
                if (ls <= unpackf(k0) + THETA) {
                    const int tj = g * 4 + j;
                    const int p = atomicAdd(&ecnt[wv][tj], 1);
                    if (p < ECT)
                        elist[wv][tj][p] =
                            (((unsigned)(bkl[j] & 0xffffull)) << 16) | f2h_bits(ls);
                }
            }
        }

        // broadcast winner + gmin to owner lanes (frozen mux)
        unsigned bc0 = (unsigned)(gk[0] & 0xffffffffull);
        unsigned bc1 = (unsigned)(gk[1] & 0xffffffffull);
        unsigned bc2 = (unsigned)(gk[2] & 0xffffffffull);
        unsigned bc3 = (unsigned)(gk[3] & 0xffffffffull);
        float gm0 = unpackf(gk[0]), gm1 = unpackf(gk[1]);
        float gm2 = unpackf(gk[2]), gm3 = unpackf(gk[3]);
        const int srcl = (c4 >> 2) << 4;
        const unsigned w0 = __shfl(bc0, srcl, 64);
        const unsigned w1 = __shfl(bc1, srcl, 64);
        const unsigned w2 = __shfl(bc2, srcl, 64);
        const unsigned w3 = __shfl(bc3, srcl, 64);
        const float s0 = __shfl(gm0, srcl, 64);
        const float s1 = __shfl(gm1, srcl, 64);
        const float s2 = __shfl(gm2, srcl, 64);
        const float s3 = __shfl(gm3, srcl, 64);
        const unsigned wa = (c4 & 1) ? w1 : w0;
        const unsigned wb = (c4 & 1) ? w3 : w2;
        const unsigned wincand = (c4 & 2) ? wb : wa;
        const float sa = (c4 & 1) ? s1 : s0;
        const float sb = (c4 & 1) ? s3 : s2;
        const float gminmy = (c4 & 2) ? sb : sa;

        // ---- exact winner: 4-lane relay (frozen) ----
        unsigned long long bestk;
        {
            const float* wp = cblf + (size_t)wincand * D_;
            float4 wA = *reinterpret_cast<const float4*>(wp + g * 8);
            float4 wB = *reinterpret_cast<const float4*>(wp + g * 8 + 4);
            float4 nA = *reinterpret_cast<const float4*>(wp + 32 + g * 8);
            float4 nB = *reinterpret_cast<const float4*>(wp + 32 + g * 8 + 4);
            float a0 = 0.0f;
            #pragma unroll
            for (int s = 0; s < 32; ++s) {
                const int kk = s >> 2;
                if ((s & 3) == g) {
                    a0 = fmaf(wA.x, r_[kk * 8 + 0], a0);
                    a0 = fmaf(wA.y, r_[kk * 8 + 1], a0);
                    a0 = fmaf(wA.z, r_[kk * 8 + 2], a0);
                    a0 = fmaf(wA.w, r_[kk * 8 + 3], a0);
                    a0 = fmaf(wB.x, r_[kk * 8 + 4], a0);
                    a0 = fmaf(wB.y, r_[kk * 8 + 5], a0);
                    a0 = fmaf(wB.z, r_[kk * 8 + 6], a0);
                    a0 = fmaf(wB.w, r_[kk * 8 + 7], a0);
                    wA = nA; wB = nB;
                    if (kk + 2 < 8) {
                        nA = *reinterpret_cast<const float4*>(wp + (kk + 2) * 32 + g * 8);
                        nB = *reinterpret_cast<const float4*>(wp + (kk + 2) * 32 + g * 8 + 4);
                    }
                }
                a0 = __shfl(a0, (lane + 48) & 63, 64);
            }
            a0 = __shfl(a0, c4, 64);
            const float scw = __fadd_rn(__fsub_rn(rrv, __fmul_rn(2.0f, a0)), wwl[wincand]);
            bestk = packkey(scw, wincand);
        }

        // ---- extras: per-token relay with gmin filter (frozen) ----
        {
            const int myn = min(ecnt[wv][c4], ECT);
            const float gth = gminmy + THETA + 0.5f;   // f16-rounding margin
            #pragma unroll 1
            for (int i = 0; i < myn; ++i) {
                const unsigned e  = elist[wv][c4][i];
                const unsigned ec = e >> 16;
                const float hsc = h_bits2f((unsigned short)(e & 0xffffu));
                if (ec == wincand || hsc > gth) continue;
                const float* ep = cblf + (size_t)ec * D_;
                float4 wA = *reinterpret_cast<const float4*>(ep + g * 8);
                float4 wB = *reinterpret_cast<const float4*>(ep + g * 8 + 4);
                float4 nA = *reinterpret_cast<const float4*>(ep + 32 + g * 8);
                float4 nB = *reinterpret_cast<const float4*>(ep + 32 + g * 8 + 4);
                float q = 0.0f;
                #pragma unroll
                for (int s = 0; s < 32; ++s) {
                    const int kk = s >> 2;
                    if ((s & 3) == g) {
                        q = fmaf(wA.x, r_[kk * 8 + 0], q);
                        q = fmaf(wA.y, r_[kk * 8 + 1], q);
                        q = fmaf(wA.z, r_[kk * 8 + 2], q);
                        q = fmaf(wA.w, r_[kk * 8 + 3], q);
                        q = fmaf(wB.x, r_[kk * 8 + 4], q);
                        q = fmaf(wB.y, r_[kk * 8 + 5], q);
                        q = fmaf(wB.z, r_[kk * 8 + 6], q);
                        q = fmaf(wB.w, r_[kk * 8 + 7], q);
                        wA = nA; wB = nB;
                        if (kk + 2 < 8) {
                            nA = *reinterpret_cast<const float4*>(ep + (kk + 2) * 32 + g * 8);
                            nB = *reinterpret_cast<const float4*>(ep + (kk + 2) * 32 + g * 8 + 4);
                        }
                    }
                    q = __shfl(q, (lane + 48) & 63, 64);
                }
                q = __shfl(q, c4, 64);
                const float sce = __fadd_rn(__fsub_rn(rrv, __fmul_rn(2.0f, q)), wwl[ec]);
                const unsigned long long k2 = packkey(sce, ec);
                if (k2 < bestk) bestk = k2;
            }
        }

        const unsigned fc = (unsigned)(bestk & 0xffffffffull);
        if (g == 0)
            out[(size_t)B_ * D_ * T_ + ((size_t)b * L_ + l) * T_ + tl] = (float)fc;

        // ---- residual update (frozen element-wise f32) ----
        {
            const float* up = cblf + (size_t)fc * D_;
            #pragma unroll
            for (int kk = 0; kk < 8; ++kk) {
                const float4 ua = *reinterpret_cast<const float4*>(up + kk * 32 + g * 8);
                const float4 ub = *reinterpret_cast<const float4*>(up + kk * 32 + g * 8 + 4);
                r_[kk * 8 + 0] = __fsub_rn(r_[kk * 8 + 0], ua.x);
                r_[kk * 8 + 1] = __fsub_rn(r_[kk * 8 + 1], ua.y);
                r_[kk * 8 + 2] = __fsub_rn(r_[kk * 8 + 2], ua.z);
                r_[kk * 8 + 3] = __fsub_rn(r_[kk * 8 + 3], ua.w);
                r_[kk * 8 + 4] = __fsub_rn(r_[kk * 8 + 4], ub.x);
                r_[kk * 8 + 5] = __fsub_rn(r_[kk * 8 + 5], ub.y);
                r_[kk * 8 + 6] = __fsub_rn(r_[kk * 8 + 6], ub.z);
                r_[kk * 8 + 7] = __fsub_rn(r_[kk * 8 + 7], ub.w);
            }
        }
    }

    // epilogue (frozen): quantized = x - r_final
    #pragma unroll
    for (int kk = 0; kk < 8; ++kk)
        #pragma unroll
        for (int e = 0; e < 8; ++e) {
            const size_t gi = xbase + (size_t)(kk * 32 + g * 8 + e) * T_;
            out[gi] = __fsub_rn(x[gi], r_[kk * 8 + e]);
        }
}

extern "C" void kernel_launch(void* const* d_in, const int* in_sizes, int n_in,
                              void* d_out, int out_size, void* d_ws, size_t ws_size,
                              hipStream_t stream) {
    const float* x  = (const float*)d_in[0];
    const float* cb = (const float*)d_in[1];
    float* out = (float*)d_out;
    float*    ww    = (float*)d_ws;                       // 32 KB
    _Float16* cb16p = (_Float16*)((char*)d_ws + 32768);   // 4 MB (tile-image)

    hipLaunchKernelGGL(rvq_ww_kernel,   dim3((L_ * K_) / 4), dim3(256), 0, stream, cb, ww);
    hipLaunchKernelGGL(rvq_cvtp_kernel, dim3(1024), dim3(256), 0, stream, cb, cb16p);
    hipLaunchKernelGGL(rvq_main_kernel, dim3((B_ * T_) / 128), dim3(512), 0, stream,
                       x, cb, cb16p, ww, out);
}